// Round 10
// baseline (300.475 us; speedup 1.0000x reference)
//
#include <hip/hip_runtime.h>
#include <math.h>

// PLDA pairwise scorer, eigendecomposition-free, all-symmetric formulation.
// Z = S_wn^{-1/2} via degree-6 Chebyshev in P = S_wn - I; M = Z*SB*Z;
// F = f0(inv_s*M) via degree-24 bivariate Chebyshev
// (F = G0 + T5*G1 + T10*G2 + T15*G3 + T20*G4); B = (63/64)*inv_s*Z*F*Z.
// out = 2 v_i^T B v_j - q_i - q_j - log_div.
// Fused kernels: phase-1 computes the FULL first product into LDS (64 KB
// dual-bf16), phase-2 computes dependent strip products from LDS. 15 dispatches.

#define D 128
#define NCLS 256
#define NPC 64
#define MTEST 8192
#define COUNT (NCLS*NPC)

// ws float-offset layout
#define fMC    0                      // McT bf16 [128][256]
#define fMEAN  16384                  // 128 f32
#define fSCAL  16640                  // scalars (256 f32)
#define fMAT   32768                  // 25 dual-plane matrices x 16384 fl
#define fSWRAW 442368                 // 16384 f32 Gram sum
#define fPART  458752                 // 64*16384 f32 (dead after k_reduce)
#define fU     458752
#define fV     983040
#define fQ     1507328
#define fBBF   1515520

// matrix slots
#define sP   0
#define sSB  1
#define sP2  2
#define sP3  3
#define sP4  4
#define sZ   5
#define sMm  7
#define sC2  8
#define sXH  10
#define sT2  11
#define sT3  12
#define sT4  13
#define sT5  14
#define sT10 15
#define sT15 16
#define sT20 17
#define sG0  18   // G0..G4 = 18..22
#define sF   23

using short8 = __attribute__((ext_vector_type(8))) short;
using f32x4  = __attribute__((ext_vector_type(4))) float;

__device__ inline unsigned short f2bf(float f) {
  unsigned u = __float_as_uint(f);
  unsigned r = u + 0x7FFFu + ((u >> 16) & 1u);
  return (unsigned short)(r >> 16);
}
__device__ inline float bf2f(unsigned short h) {
  return __uint_as_float(((unsigned)h) << 16);
}
__device__ inline float valU(const unsigned short* m, int idx) {
  return bf2f(m[idx]) + bf2f(m[idx + 16384]);
}
__device__ inline void storeDual(unsigned short* m, int idx, float g) {
  unsigned short hb = f2bf(g);
  m[idx] = hb;
  m[16384 + idx] = f2bf(g - bf2f(hb));
}
__device__ inline unsigned short* MS(float* ws, int m) {
  return (unsigned short*)(ws + fMAT) + (size_t)m * 32768;
}
// LDS full 128x128 plane, swizzled; plane stride 16384 ushorts
__device__ inline short8 lds8(const unsigned short* L, int row, int colk) {
  unsigned u = ((unsigned)(row * 128 + colk)) ^ (((unsigned)(row & 7)) << 3);
  return *(const short8*)(L + u);
}
__device__ inline void ldsPutDual(unsigned short* L, int row, int col, float g) {
  unsigned u = ((unsigned)(row * 128 + col)) ^ (((unsigned)(row & 7)) << 3);
  unsigned short hb = f2bf(g);
  L[u] = hb;
  L[16384 + u] = f2bf(g - bf2f(hb));
}

// ---------------- strip matmul: C = alpha*(A x B) [+ beta*E1] [+ delta*I]; returns sum g^2
__device__ float mm_body(const unsigned short* A, const unsigned short* B,
                         unsigned short* C, const unsigned short* E1,
                         float alpha, float beta, float delta, int brow) {
  int tid = threadIdx.x;
  int w = tid >> 6, lane = tid & 63;
  int wcol = w * 32;
  f32x4 acc[2][2] = {};
  #pragma unroll
  for (int ks = 0; ks < 4; ks++) {
    int kb = ks * 32 + (lane >> 4) * 8;
    short8 ah[2], al[2], bh[2], bl[2];
    #pragma unroll
    for (int mt = 0; mt < 2; mt++) {
      int r = brow + mt * 16 + (lane & 15);
      ah[mt] = *(const short8*)(A + r * 128 + kb);
      al[mt] = *(const short8*)(A + 16384 + r * 128 + kb);
    }
    #pragma unroll
    for (int nt = 0; nt < 2; nt++) {
      int c = wcol + nt * 16 + (lane & 15);
      bh[nt] = *(const short8*)(B + c * 128 + kb);
      bl[nt] = *(const short8*)(B + 16384 + c * 128 + kb);
    }
    #pragma unroll
    for (int mt = 0; mt < 2; mt++)
      #pragma unroll
      for (int nt = 0; nt < 2; nt++) {
        f32x4 a0 = acc[mt][nt];
        a0 = __builtin_amdgcn_mfma_f32_16x16x32_bf16(ah[mt], bh[nt], a0, 0, 0, 0);
        a0 = __builtin_amdgcn_mfma_f32_16x16x32_bf16(al[mt], bh[nt], a0, 0, 0, 0);
        a0 = __builtin_amdgcn_mfma_f32_16x16x32_bf16(ah[mt], bl[nt], a0, 0, 0, 0);
        acc[mt][nt] = a0;
      }
  }
  float tsum = 0.f;
  #pragma unroll
  for (int mt = 0; mt < 2; mt++)
    #pragma unroll
    for (int nt = 0; nt < 2; nt++)
      #pragma unroll
      for (int r = 0; r < 4; r++) {
        int row = brow + mt * 16 + (lane >> 4) * 4 + r;
        int col = wcol + nt * 16 + (lane & 15);
        int idx = row * 128 + col;
        float g = acc[mt][nt][r] * alpha;
        if (E1) g += beta * valU(E1, idx);
        if (row == col) g += delta;
        storeDual(C, idx, g);
        tsum += g * g;
      }
  return tsum;
}

// ---------------- K1: Gram partials + class means ----------------
__global__ __launch_bounds__(256) void k_gt_partial(const float* __restrict__ X, float* __restrict__ ws) {
  __shared__ unsigned short xt[128 * 256]; // 64 KB
  int b = blockIdx.x, tid = threadIdx.x;
  const float* Xc = X + b * 256 * D;
  for (int idx = tid; idx < 256 * D; idx += 256) {
    int s = idx >> 7, d = idx & 127;
    unsigned byte = ((unsigned)(d * 512 + s * 2)) ^ (((unsigned)(d & 7)) << 4);
    *(unsigned short*)((char*)xt + byte) = f2bf(Xc[idx]);
  }
  {
    int d = tid & 127;
    for (int cc = (tid >> 7); cc < 4; cc += 2) {
      const float* p = Xc + cc * 64 * D + d;
      float s = 0.f;
      #pragma unroll
      for (int n = 0; n < 64; n++) s += p[n * D];
      ((unsigned short*)ws)[d * 256 + (b * 4 + cc)] = f2bf(s * (1.0f / 64.0f));
    }
  }
  __syncthreads();
  int w = tid >> 6, lane = tid & 63;
  int wr = (w >> 1) * 64, wc = (w & 1) * 64;
  f32x4 acc[4][4] = {};
  for (int ks = 0; ks < 8; ks++) {
    int kb = ks * 32 + (lane >> 4) * 8;
    short8 af[4];
    #pragma unroll
    for (int mt = 0; mt < 4; mt++) {
      int r = wr + mt * 16 + (lane & 15);
      unsigned byte = ((unsigned)(r * 512 + kb * 2)) ^ (((unsigned)(r & 7)) << 4);
      af[mt] = *(short8*)((char*)xt + byte);
    }
    #pragma unroll
    for (int nt = 0; nt < 4; nt++) {
      int c = wc + nt * 16 + (lane & 15);
      unsigned byte = ((unsigned)(c * 512 + kb * 2)) ^ (((unsigned)(c & 7)) << 4);
      short8 bfr = *(short8*)((char*)xt + byte);
      #pragma unroll
      for (int mt = 0; mt < 4; mt++)
        acc[mt][nt] = __builtin_amdgcn_mfma_f32_16x16x32_bf16(af[mt], bfr, acc[mt][nt], 0, 0, 0);
    }
  }
  float* outp = ws + fPART + b * 16384;
  #pragma unroll
  for (int mt = 0; mt < 4; mt++)
    #pragma unroll
    for (int nt = 0; nt < 4; nt++)
      #pragma unroll
      for (int r = 0; r < 4; r++) {
        int row = wr + mt * 16 + (lane >> 4) * 4 + r;
        int col = wc + nt * 16 + (lane & 15);
        outp[row * 128 + col] = acc[mt][nt][r];
      }
}

// ---------------- K2: reduce partials; blk0: mean; blk1: inv_s ----------------
__global__ void k_reduce(float* __restrict__ ws) {
  __shared__ float red2[4];
  int tid = threadIdx.x;
  int idx = blockIdx.x * 256 + tid;
  const float* part = ws + fPART;
  float s = 0.f;
  #pragma unroll 8
  for (int p = 0; p < 64; p++) s += part[p * 16384 + idx];
  ws[fSWRAW + idx] = s;
  if (blockIdx.x == 0 && tid < 128) {
    const unsigned short* McT = (const unsigned short*)ws;
    float m = 0.f;
    for (int k = 0; k < 256; k++) m += bf2f(McT[tid * 256 + k]);
    ws[fMEAN + tid] = m * (1.0f / 256.0f);
  }
  if (blockIdx.x == 1) {
    float v = 0.f;
    if (tid < 128) {
      float gdd = 0.f;
      for (int p = 0; p < 64; p++) gdd += part[p * 16384 + tid * 129];
      const unsigned short* McT = (const unsigned short*)ws;
      float nrm = 0.f;
      for (int k = 0; k < 256; k++) { float x = bf2f(McT[tid * 256 + k]); nrm += x * x; }
      v = gdd * (1.0f / COUNT) - nrm * (1.0f / 256.0f);
    }
    #pragma unroll
    for (int off = 32; off > 0; off >>= 1) v += __shfl_down(v, off);
    if ((tid & 63) == 0) red2[tid >> 6] = v;
    __syncthreads();
    if (tid == 0) {
      float inv_s = 128.0f / (red2[0] + red2[1] + red2[2] + red2[3]);
      ws[fSCAL + 1] = inv_s;
      ws[fSCAL + 7] = 0.984375f * inv_s;
    }
  }
}

// ---------------- K3: SB strip (K=256 MFMA) + P = S_wn - I strip ----------------
__global__ __launch_bounds__(256) void k_sbp(float* __restrict__ ws) {
  const unsigned short* Mc = (const unsigned short*)ws;
  const float* mv = ws + fMEAN;
  const float* swraw = ws + fSWRAW;
  float inv_s = ws[fSCAL + 1];
  unsigned short* SB = MS(ws, sSB);
  unsigned short* P = MS(ws, sP);
  int tid = threadIdx.x, b = blockIdx.x;
  int w = tid >> 6, lane = tid & 63;
  int brow = b * 32, wcol = w * 32;
  f32x4 acc[2][2] = {};
  for (int ks = 0; ks < 8; ks++) {
    int kb = ks * 32 + (lane >> 4) * 8;
    short8 af[2], bfv[2];
    #pragma unroll
    for (int mt = 0; mt < 2; mt++) {
      int r = brow + mt * 16 + (lane & 15);
      af[mt] = *(const short8*)(Mc + r * 256 + kb);
    }
    #pragma unroll
    for (int nt = 0; nt < 2; nt++) {
      int c = wcol + nt * 16 + (lane & 15);
      bfv[nt] = *(const short8*)(Mc + c * 256 + kb);
    }
    #pragma unroll
    for (int mt = 0; mt < 2; mt++)
      #pragma unroll
      for (int nt = 0; nt < 2; nt++)
        acc[mt][nt] = __builtin_amdgcn_mfma_f32_16x16x32_bf16(af[mt], bfv[nt], acc[mt][nt], 0, 0, 0);
  }
  #pragma unroll
  for (int mt = 0; mt < 2; mt++)
    #pragma unroll
    for (int nt = 0; nt < 2; nt++)
      #pragma unroll
      for (int r = 0; r < 4; r++) {
        int row = brow + mt * 16 + (lane >> 4) * 4 + r;
        int col = wcol + nt * 16 + (lane & 15);
        int idx = row * 128 + col;
        float g = acc[mt][nt][r] * (1.0f / 256.0f) - mv[row] * mv[col];
        storeDual(SB, idx, g);
        float s = (swraw[idx] * (1.0f / COUNT) - g - mv[row] * mv[col]) * inv_s;
        storeDual(P, idx, s - ((row == col) ? 1.0f : 0.0f));
      }
}

// ---------------- K4: full P2 (LDS+global) -> strips P3, P4 (+tr P^8) ----------------
__global__ __launch_bounds__(256) void k_p234(float* __restrict__ ws) {
  __shared__ unsigned short sL[32768]; // 64 KB: full dual P2
  float* scal = ws + fSCAL;
  const unsigned short* P = MS(ws, sP);
  unsigned short* P2 = MS(ws, sP2);
  unsigned short* P3 = MS(ws, sP3);
  unsigned short* P4 = MS(ws, sP4);
  int tid = threadIdx.x, b = blockIdx.x;
  int w = tid >> 6, lane = tid & 63;
  int wcol = w * 32, brow = b * 32;
  // phase 1: full P2 = P*P
  {
    f32x4 acc[8][2] = {};
    for (int ks = 0; ks < 4; ks++) {
      int kb = ks * 32 + (lane >> 4) * 8;
      short8 bh[2], bl[2];
      #pragma unroll
      for (int nt = 0; nt < 2; nt++) {
        int c = wcol + nt * 16 + (lane & 15);
        bh[nt] = *(const short8*)(P + c * 128 + kb);
        bl[nt] = *(const short8*)(P + 16384 + c * 128 + kb);
      }
      #pragma unroll
      for (int mt = 0; mt < 8; mt++) {
        int r = mt * 16 + (lane & 15);
        short8 ah = *(const short8*)(P + r * 128 + kb);
        short8 al = *(const short8*)(P + 16384 + r * 128 + kb);
        #pragma unroll
        for (int nt = 0; nt < 2; nt++) {
          f32x4 a0 = acc[mt][nt];
          a0 = __builtin_amdgcn_mfma_f32_16x16x32_bf16(ah, bh[nt], a0, 0, 0, 0);
          a0 = __builtin_amdgcn_mfma_f32_16x16x32_bf16(al, bh[nt], a0, 0, 0, 0);
          a0 = __builtin_amdgcn_mfma_f32_16x16x32_bf16(ah, bl[nt], a0, 0, 0, 0);
          acc[mt][nt] = a0;
        }
      }
    }
    #pragma unroll
    for (int mt = 0; mt < 8; mt++)
      #pragma unroll
      for (int nt = 0; nt < 2; nt++)
        #pragma unroll
        for (int r = 0; r < 4; r++) {
          int row = mt * 16 + (lane >> 4) * 4 + r;
          int col = wcol + nt * 16 + (lane & 15);
          float g = acc[mt][nt][r];
          ldsPutDual(sL, row, col, g);
          storeDual(P2, row * 128 + col, g);
        }
  }
  __syncthreads();
  // phase 2: P3 = P2s*P, P4 = P2s*P2(lds); trace ||P4||^2 strip
  float tsum = 0.f;
  {
    f32x4 a3[2][2] = {}, a4[2][2] = {};
    for (int ks = 0; ks < 4; ks++) {
      int kb = ks * 32 + (lane >> 4) * 8;
      short8 ah[2], al[2], b3h[2], b3l[2], b4h[2], b4l[2];
      #pragma unroll
      for (int mt = 0; mt < 2; mt++) {
        int r = brow + mt * 16 + (lane & 15);
        ah[mt] = lds8(sL, r, kb);
        al[mt] = lds8(sL + 16384, r, kb);
      }
      #pragma unroll
      for (int nt = 0; nt < 2; nt++) {
        int c = wcol + nt * 16 + (lane & 15);
        b3h[nt] = *(const short8*)(P + c * 128 + kb);
        b3l[nt] = *(const short8*)(P + 16384 + c * 128 + kb);
        b4h[nt] = lds8(sL, c, kb);
        b4l[nt] = lds8(sL + 16384, c, kb);
      }
      #pragma unroll
      for (int mt = 0; mt < 2; mt++)
        #pragma unroll
        for (int nt = 0; nt < 2; nt++) {
          f32x4 x3 = a3[mt][nt];
          x3 = __builtin_amdgcn_mfma_f32_16x16x32_bf16(ah[mt], b3h[nt], x3, 0, 0, 0);
          x3 = __builtin_amdgcn_mfma_f32_16x16x32_bf16(al[mt], b3h[nt], x3, 0, 0, 0);
          x3 = __builtin_amdgcn_mfma_f32_16x16x32_bf16(ah[mt], b3l[nt], x3, 0, 0, 0);
          a3[mt][nt] = x3;
          f32x4 x4 = a4[mt][nt];
          x4 = __builtin_amdgcn_mfma_f32_16x16x32_bf16(ah[mt], b4h[nt], x4, 0, 0, 0);
          x4 = __builtin_amdgcn_mfma_f32_16x16x32_bf16(al[mt], b4h[nt], x4, 0, 0, 0);
          x4 = __builtin_amdgcn_mfma_f32_16x16x32_bf16(ah[mt], b4l[nt], x4, 0, 0, 0);
          a4[mt][nt] = x4;
        }
    }
    #pragma unroll
    for (int mt = 0; mt < 2; mt++)
      #pragma unroll
      for (int nt = 0; nt < 2; nt++)
        #pragma unroll
        for (int r = 0; r < 4; r++) {
          int row = brow + mt * 16 + (lane >> 4) * 4 + r;
          int col = wcol + nt * 16 + (lane & 15);
          int idx = row * 128 + col;
          storeDual(P3, idx, a3[mt][nt][r]);
          float g4 = a4[mt][nt][r];
          storeDual(P4, idx, g4);
          tsum += g4 * g4;
        }
  }
  #pragma unroll
  for (int off = 32; off > 0; off >>= 1) tsum += __shfl_down(tsum, off);
  __syncthreads();
  float* red = (float*)sL;
  if (lane == 0) red[w] = tsum;
  __syncthreads();
  if (tid == 0) scal[60 + b] = red[0] + red[1] + red[2] + red[3];
}

// ---------------- K5: P5,P6 in-reg + Z = sum beta_k P^k ----------------
__global__ __launch_bounds__(256) void k_z(float* __restrict__ ws) {
  __shared__ float cj[7];
  __shared__ float bt[7];
  float* scal = ws + fSCAL;
  const unsigned short *P = MS(ws, sP), *P2 = MS(ws, sP2),
    *P3 = MS(ws, sP3), *P4 = MS(ws, sP4);
  unsigned short* Z = MS(ws, sZ);
  int tid = threadIdx.x, b = blockIdx.x;
  float trP8 = scal[60] + scal[61] + scal[62] + scal[63];
  float a = 1.05f * sqrtf(sqrtf(sqrtf(fmaxf(trP8, 1e-30f))));
  a = fminf(a, 0.95f);
  if (tid < 7) {
    const float PI = 3.14159265358979f;
    float s = 0.f;
    for (int i = 0; i < 64; i++) {
      float th = (i + 0.5f) * (PI / 64.0f);
      float x = cosf(th);
      s += (1.0f / sqrtf(1.0f + a * x)) * cosf((float)tid * th);
    }
    cj[tid] = s * (2.0f / 64.0f);
  }
  __syncthreads();
  if (tid == 0) {
    float c0h = 0.5f * cj[0];
    float m0 = c0h - cj[2] + cj[4] - cj[6];
    float m1 = cj[1] - 3.0f * cj[3] + 5.0f * cj[5];
    float m2 = 2.0f * cj[2] - 8.0f * cj[4] + 18.0f * cj[6];
    float m3 = 4.0f * cj[3] - 20.0f * cj[5];
    float m4 = 8.0f * cj[4] - 48.0f * cj[6];
    float m5 = 16.0f * cj[5];
    float m6 = 32.0f * cj[6];
    float ia = 1.0f / a, p = 1.f;
    bt[0] = m0;
    p *= ia; bt[1] = m1 * p;
    p *= ia; bt[2] = m2 * p;
    p *= ia; bt[3] = m3 * p;
    p *= ia; bt[4] = m4 * p;
    p *= ia; bt[5] = m5 * p;
    p *= ia; bt[6] = m6 * p;
  }
  __syncthreads();
  int w = tid >> 6, lane = tid & 63;
  int brow = b * 32, wcol = w * 32;
  f32x4 a5[2][2] = {}, a6[2][2] = {};
  #pragma unroll
  for (int ks = 0; ks < 4; ks++) {
    int kb = ks * 32 + (lane >> 4) * 8;
    short8 ah[2], al[2], b5h[2], b5l[2], b6h[2], b6l[2];
    #pragma unroll
    for (int mt = 0; mt < 2; mt++) {
      int r = brow + mt * 16 + (lane & 15);
      ah[mt] = *(const short8*)(P4 + r * 128 + kb);
      al[mt] = *(const short8*)(P4 + 16384 + r * 128 + kb);
    }
    #pragma unroll
    for (int nt = 0; nt < 2; nt++) {
      int c = wcol + nt * 16 + (lane & 15);
      b5h[nt] = *(const short8*)(P + c * 128 + kb);
      b5l[nt] = *(const short8*)(P + 16384 + c * 128 + kb);
      b6h[nt] = *(const short8*)(P2 + c * 128 + kb);
      b6l[nt] = *(const short8*)(P2 + 16384 + c * 128 + kb);
    }
    #pragma unroll
    for (int mt = 0; mt < 2; mt++)
      #pragma unroll
      for (int nt = 0; nt < 2; nt++) {
        f32x4 x5 = a5[mt][nt];
        x5 = __builtin_amdgcn_mfma_f32_16x16x32_bf16(ah[mt], b5h[nt], x5, 0, 0, 0);
        x5 = __builtin_amdgcn_mfma_f32_16x16x32_bf16(al[mt], b5h[nt], x5, 0, 0, 0);
        x5 = __builtin_amdgcn_mfma_f32_16x16x32_bf16(ah[mt], b5l[nt], x5, 0, 0, 0);
        a5[mt][nt] = x5;
        f32x4 x6 = a6[mt][nt];
        x6 = __builtin_amdgcn_mfma_f32_16x16x32_bf16(ah[mt], b6h[nt], x6, 0, 0, 0);
        x6 = __builtin_amdgcn_mfma_f32_16x16x32_bf16(al[mt], b6h[nt], x6, 0, 0, 0);
        x6 = __builtin_amdgcn_mfma_f32_16x16x32_bf16(ah[mt], b6l[nt], x6, 0, 0, 0);
        a6[mt][nt] = x6;
      }
  }
  #pragma unroll
  for (int mt = 0; mt < 2; mt++)
    #pragma unroll
    for (int nt = 0; nt < 2; nt++)
      #pragma unroll
      for (int r = 0; r < 4; r++) {
        int row = brow + mt * 16 + (lane >> 4) * 4 + r;
        int col = wcol + nt * 16 + (lane & 15);
        int idx = row * 128 + col;
        float dg = (row == col) ? 1.0f : 0.0f;
        float z = bt[0] * dg + bt[1] * valU(P, idx) + bt[2] * valU(P2, idx) +
                  bt[3] * valU(P3, idx) + bt[4] * valU(P4, idx) +
                  bt[5] * a5[mt][nt][r] + bt[6] * a6[mt][nt][r];
        storeDual(Z, idx, z);
      }
}

// ---------------- K6: full ZSB (LDS) -> Mm strip ----------------
__global__ __launch_bounds__(256) void k_msb(float* __restrict__ ws) {
  __shared__ unsigned short sL[32768];
  const unsigned short* Z = MS(ws, sZ);
  const unsigned short* SB = MS(ws, sSB);
  unsigned short* Mm = MS(ws, sMm);
  int tid = threadIdx.x, b = blockIdx.x;
  int w = tid >> 6, lane = tid & 63;
  int wcol = w * 32, brow = b * 32;
  {
    f32x4 acc[8][2] = {};
    for (int ks = 0; ks < 4; ks++) {
      int kb = ks * 32 + (lane >> 4) * 8;
      short8 bh[2], bl[2];
      #pragma unroll
      for (int nt = 0; nt < 2; nt++) {
        int c = wcol + nt * 16 + (lane & 15);
        bh[nt] = *(const short8*)(SB + c * 128 + kb);
        bl[nt] = *(const short8*)(SB + 16384 + c * 128 + kb);
      }
      #pragma unroll
      for (int mt = 0; mt < 8; mt++) {
        int r = mt * 16 + (lane & 15);
        short8 ah = *(const short8*)(Z + r * 128 + kb);
        short8 al = *(const short8*)(Z + 16384 + r * 128 + kb);
        #pragma unroll
        for (int nt = 0; nt < 2; nt++) {
          f32x4 a0 = acc[mt][nt];
          a0 = __builtin_amdgcn_mfma_f32_16x16x32_bf16(ah, bh[nt], a0, 0, 0, 0);
          a0 = __builtin_amdgcn_mfma_f32_16x16x32_bf16(al, bh[nt], a0, 0, 0, 0);
          a0 = __builtin_amdgcn_mfma_f32_16x16x32_bf16(ah, bl[nt], a0, 0, 0, 0);
          acc[mt][nt] = a0;
        }
      }
    }
    #pragma unroll
    for (int mt = 0; mt < 8; mt++)
      #pragma unroll
      for (int nt = 0; nt < 2; nt++)
        #pragma unroll
        for (int r = 0; r < 4; r++) {
          int row = mt * 16 + (lane >> 4) * 4 + r;
          int col = wcol + nt * 16 + (lane & 15);
          ldsPutDual(sL, row, col, acc[mt][nt][r]);
        }
  }
  __syncthreads();
  {
    f32x4 acc[2][2] = {};
    for (int ks = 0; ks < 4; ks++) {
      int kb = ks * 32 + (lane >> 4) * 8;
      short8 ah[2], al[2], bh[2], bl[2];
      #pragma unroll
      for (int mt = 0; mt < 2; mt++) {
        int r = brow + mt * 16 + (lane & 15);
        ah[mt] = lds8(sL, r, kb);
        al[mt] = lds8(sL + 16384, r, kb);
      }
      #pragma unroll
      for (int nt = 0; nt < 2; nt++) {
        int c = wcol + nt * 16 + (lane & 15);
        bh[nt] = *(const short8*)(Z + c * 128 + kb);
        bl[nt] = *(const short8*)(Z + 16384 + c * 128 + kb);
      }
      #pragma unroll
      for (int mt = 0; mt < 2; mt++)
        #pragma unroll
        for (int nt = 0; nt < 2; nt++) {
          f32x4 a0 = acc[mt][nt];
          a0 = __builtin_amdgcn_mfma_f32_16x16x32_bf16(ah[mt], bh[nt], a0, 0, 0, 0);
          a0 = __builtin_amdgcn_mfma_f32_16x16x32_bf16(al[mt], bh[nt], a0, 0, 0, 0);
          a0 = __builtin_amdgcn_mfma_f32_16x16x32_bf16(ah[mt], bl[nt], a0, 0, 0, 0);
          acc[mt][nt] = a0;
        }
    }
    #pragma unroll
    for (int mt = 0; mt < 2; mt++)
      #pragma unroll
      for (int nt = 0; nt < 2; nt++)
        #pragma unroll
        for (int r = 0; r < 4; r++) {
          int row = brow + mt * 16 + (lane >> 4) * 4 + r;
          int col = wcol + nt * 16 + (lane & 15);
          storeDual(Mm, row * 128 + col, acc[mt][nt][r]);
        }
  }
}

// ---------------- K7: full C2 (LDS+global) -> C4 strip trace (tr M^8) ----------------
__global__ __launch_bounds__(256) void k_c24(float* __restrict__ ws) {
  __shared__ unsigned short sL[32768];
  float* scal = ws + fSCAL;
  const unsigned short* Mm = MS(ws, sMm);
  unsigned short* C2 = MS(ws, sC2);
  int tid = threadIdx.x, b = blockIdx.x;
  int w = tid >> 6, lane = tid & 63;
  int wcol = w * 32, brow = b * 32;
  {
    f32x4 acc[8][2] = {};
    for (int ks = 0; ks < 4; ks++) {
      int kb = ks * 32 + (lane >> 4) * 8;
      short8 bh[2], bl[2];
      #pragma unroll
      for (int nt = 0; nt < 2; nt++) {
        int c = wcol + nt * 16 + (lane & 15);
        bh[nt] = *(const short8*)(Mm + c * 128 + kb);
        bl[nt] = *(const short8*)(Mm + 16384 + c * 128 + kb);
      }
      #pragma unroll
      for (int mt = 0; mt < 8; mt++) {
        int r = mt * 16 + (lane & 15);
        short8 ah = *(const short8*)(Mm + r * 128 + kb);
        short8 al = *(const short8*)(Mm + 16384 + r * 128 + kb);
        #pragma unroll
        for (int nt = 0; nt < 2; nt++) {
          f32x4 a0 = acc[mt][nt];
          a0 = __builtin_amdgcn_mfma_f32_16x16x32_bf16(ah, bh[nt], a0, 0, 0, 0);
          a0 = __builtin_amdgcn_mfma_f32_16x16x32_bf16(al, bh[nt], a0, 0, 0, 0);
          a0 = __builtin_amdgcn_mfma_f32_16x16x32_bf16(ah, bl[nt], a0, 0, 0, 0);
          acc[mt][nt] = a0;
        }
      }
    }
    #pragma unroll
    for (int mt = 0; mt < 8; mt++)
      #pragma unroll
      for (int nt = 0; nt < 2; nt++)
        #pragma unroll
        for (int r = 0; r < 4; r++) {
          int row = mt * 16 + (lane >> 4) * 4 + r;
          int col = wcol + nt * 16 + (lane & 15);
          float g = acc[mt][nt][r];
          ldsPutDual(sL, row, col, g);
          storeDual(C2, row * 128 + col, g);
        }
  }
  __syncthreads();
  float tsum = 0.f;
  {
    f32x4 acc[2][2] = {};
    for (int ks = 0; ks < 4; ks++) {
      int kb = ks * 32 + (lane >> 4) * 8;
      short8 ah[2], al[2], bh[2], bl[2];
      #pragma unroll
      for (int mt = 0; mt < 2; mt++) {
        int r = brow + mt * 16 + (lane & 15);
        ah[mt] = lds8(sL, r, kb);
        al[mt] = lds8(sL + 16384, r, kb);
      }
      #pragma unroll
      for (int nt = 0; nt < 2; nt++) {
        int c = wcol + nt * 16 + (lane & 15);
        bh[nt] = lds8(sL, c, kb);
        bl[nt] = lds8(sL + 16384, c, kb);
      }
      #pragma unroll
      for (int mt = 0; mt < 2; mt++)
        #pragma unroll
        for (int nt = 0; nt < 2; nt++) {
          f32x4 a0 = acc[mt][nt];
          a0 = __builtin_amdgcn_mfma_f32_16x16x32_bf16(ah[mt], bh[nt], a0, 0, 0, 0);
          a0 = __builtin_amdgcn_mfma_f32_16x16x32_bf16(al[mt], bh[nt], a0, 0, 0, 0);
          a0 = __builtin_amdgcn_mfma_f32_16x16x32_bf16(ah[mt], bl[nt], a0, 0, 0, 0);
          acc[mt][nt] = a0;
        }
    }
    #pragma unroll
    for (int mt = 0; mt < 2; mt++)
      #pragma unroll
      for (int nt = 0; nt < 2; nt++)
        #pragma unroll
        for (int r = 0; r < 4; r++) {
          float g = acc[mt][nt][r];
          tsum += g * g;
        }
  }
  #pragma unroll
  for (int off = 32; off > 0; off >>= 1) tsum += __shfl_down(tsum, off);
  __syncthreads();
  float* red = (float*)sL;
  if (lane == 0) red[w] = tsum;
  __syncthreads();
  if (tid == 0) scal[68 + b] = red[0] + red[1] + red[2] + red[3];
}

// interval from tr M^8
__device__ inline void interval_cs(const float* scal, float* c0o, float* iho) {
  float trM8 = scal[68] + scal[69] + scal[70] + scal[71];
  float Lam = 1.03f * sqrtf(sqrtf(sqrtf(fmaxf(trM8, 1e-37f))));
  float lo = -0.02f * Lam, hi = Lam;
  *c0o = 0.5f * (hi + lo);
  *iho = 1.0f / (0.5f * (hi - lo));
}

// ---------------- K8: XH, T2 elementwise ----------------
__global__ __launch_bounds__(256) void k_xh_t2(float* __restrict__ ws) {
  __shared__ float cs[2];
  float* scal = ws + fSCAL;
  if (threadIdx.x == 0) {
    float c0, ih;
    interval_cs(scal, &c0, &ih);
    cs[0] = c0; cs[1] = ih;
  }
  __syncthreads();
  float c0 = cs[0], ih = cs[1];
  float a2 = 2.0f * ih * ih, b2 = -4.0f * c0 * ih * ih, g2 = 2.0f * c0 * c0 * ih * ih - 1.0f;
  const unsigned short* Mm = MS(ws, sMm);
  const unsigned short* C2 = MS(ws, sC2);
  unsigned short* XH = MS(ws, sXH);
  unsigned short* T2 = MS(ws, sT2);
  int gid = blockIdx.x * 256 + threadIdx.x;
  #pragma unroll
  for (int t = 0; t < 4; t++) {
    int idx = gid * 4 + t;
    int row = idx >> 7, col = idx & 127;
    float m = valU(Mm, idx), c2v = valU(C2, idx);
    float dg = (row == col) ? 1.0f : 0.0f;
    storeDual(XH, idx, ih * m - ih * c0 * dg);
    storeDual(T2, idx, a2 * c2v + b2 * m + g2 * dg);
  }
}

// ---------------- K9: T3 = 2 XH T2 - XH (blk 0-3) | T4 = 2 T2^2 - I (blk 4-7) ----------------
__global__ __launch_bounds__(256) void k_t34(float* __restrict__ ws) {
  const unsigned short* XH = MS(ws, sXH);
  const unsigned short* T2 = MS(ws, sT2);
  if (blockIdx.x < 4) {
    mm_body(XH, T2, MS(ws, sT3), XH, 2.0f, -1.0f, 0.0f, blockIdx.x * 32);
  } else {
    mm_body(T2, T2, MS(ws, sT4), nullptr, 2.0f, 0.0f, -1.0f, (blockIdx.x - 4) * 32);
  }
}

// ---------------- K10: blk 0-3: T5 = 2 T3 T2 - XH; blk 4-19: G0..G4 ----------------
__global__ __launch_bounds__(256) void k_t5g(float* __restrict__ ws) {
  __shared__ float cs[8];
  __shared__ float sat[25];
  __shared__ float sc[25];
  float* scal = ws + fSCAL;
  int tid = threadIdx.x;
  if (blockIdx.x < 4) {
    mm_body(MS(ws, sT3), MS(ws, sT2), MS(ws, sT5), MS(ws, sXH),
            2.0f, -1.0f, 0.0f, blockIdx.x * 32);
    return;
  }
  if (tid == 0) {
    float c0, ih;
    interval_cs(scal, &c0, &ih);
    float inv_s = scal[1];
    float t0 = (1.0f / 63.0f) / inv_s;
    float x0 = fminf(fmaxf((t0 - c0) * ih, -1.0f), 1.0f);
    cs[0] = acosf(x0); cs[1] = x0;
    cs[2] = 0.984375f * inv_s / ih;
  }
  __syncthreads();
  if (tid <= 24) {
    float th = cs[0], x0 = cs[1], SCc = cs[2];
    const float PI = 3.14159265358979f;
    float v;
    if (tid == 0) v = 0.5f * SCc * (2.0f / PI) * (sinf(th) - x0 * th);
    else if (tid == 1) v = SCc * (2.0f / PI) * (0.5f * th + 0.25f * sinf(2.0f * th) - x0 * sinf(th));
    else {
      float fj = (float)tid;
      v = SCc * (2.0f / PI) *
          (0.5f * (sinf((fj + 1.0f) * th) / (fj + 1.0f) + sinf((fj - 1.0f) * th) / (fj - 1.0f))
           - x0 * sinf(fj * th) / fj);
    }
    sat[tid] = v;
    sc[tid] = 0.f;
  }
  __syncthreads();
  if (tid == 0) {
    for (int j = 24; j >= 5; --j) {
      int k = j / 5, r = j - 5 * k;
      float aj = sat[j];
      if (r == 0) sc[k * 5] += aj;
      else { sc[k * 5 + r] += 2.0f * aj; sat[5 * k - r] -= aj; }
    }
    for (int r = 0; r < 5; r++) sc[r] += sat[r];
  }
  __syncthreads();
  const unsigned short* XH = MS(ws, sXH);
  const unsigned short* T2 = MS(ws, sT2);
  const unsigned short* T3 = MS(ws, sT3);
  const unsigned short* T4 = MS(ws, sT4);
  int bg = blockIdx.x - 4;
  int base = bg * 1024 + tid * 4;
  #pragma unroll
  for (int t = 0; t < 4; t++) {
    int idx = base + t;
    int row = idx >> 7, col = idx & 127;
    float dg = (row == col) ? 1.0f : 0.0f;
    float x1 = valU(XH, idx), x2 = valU(T2, idx), x3 = valU(T3, idx), x4 = valU(T4, idx);
    #pragma unroll
    for (int k = 0; k < 5; k++) {
      float g = sc[k * 5 + 0] * dg + sc[k * 5 + 1] * x1 + sc[k * 5 + 2] * x2 +
                sc[k * 5 + 3] * x3 + sc[k * 5 + 4] * x4;
      storeDual(MS(ws, sG0 + k), idx, g);
    }
  }
}

// ---------------- K11: full T10 (LDS+global) -> strips T15, T20 ----------------
__global__ __launch_bounds__(256) void k_t101520(float* __restrict__ ws) {
  __shared__ unsigned short sL[32768];
  const unsigned short* T5 = MS(ws, sT5);
  unsigned short* T10 = MS(ws, sT10);
  unsigned short* T15 = MS(ws, sT15);
  unsigned short* T20 = MS(ws, sT20);
  int tid = threadIdx.x, b = blockIdx.x;
  int w = tid >> 6, lane = tid & 63;
  int wcol = w * 32, brow = b * 32;
  // phase1: full T10 = 2*T5*T5 - I
  {
    f32x4 acc[8][2] = {};
    for (int ks = 0; ks < 4; ks++) {
      int kb = ks * 32 + (lane >> 4) * 8;
      short8 bh[2], bl[2];
      #pragma unroll
      for (int nt = 0; nt < 2; nt++) {
        int c = wcol + nt * 16 + (lane & 15);
        bh[nt] = *(const short8*)(T5 + c * 128 + kb);
        bl[nt] = *(const short8*)(T5 + 16384 + c * 128 + kb);
      }
      #pragma unroll
      for (int mt = 0; mt < 8; mt++) {
        int r = mt * 16 + (lane & 15);
        short8 ah = *(const short8*)(T5 + r * 128 + kb);
        short8 al = *(const short8*)(T5 + 16384 + r * 128 + kb);
        #pragma unroll
        for (int nt = 0; nt < 2; nt++) {
          f32x4 a0 = acc[mt][nt];
          a0 = __builtin_amdgcn_mfma_f32_16x16x32_bf16(ah, bh[nt], a0, 0, 0, 0);
          a0 = __builtin_amdgcn_mfma_f32_16x16x32_bf16(al, bh[nt], a0, 0, 0, 0);
          a0 = __builtin_amdgcn_mfma_f32_16x16x32_bf16(ah, bl[nt], a0, 0, 0, 0);
          acc[mt][nt] = a0;
        }
      }
    }
    #pragma unroll
    for (int mt = 0; mt < 8; mt++)
      #pragma unroll
      for (int nt = 0; nt < 2; nt++)
        #pragma unroll
        for (int r = 0; r < 4; r++) {
          int row = mt * 16 + (lane >> 4) * 4 + r;
          int col = wcol + nt * 16 + (lane & 15);
          float g = 2.0f * acc[mt][nt][r] - ((row == col) ? 1.0f : 0.0f);
          ldsPutDual(sL, row, col, g);
          storeDual(T10, row * 128 + col, g);
        }
  }
  __syncthreads();
  // phase2: T15 = 2*T10s*T5 - T5; T20 = 2*T10s*T10(lds) - I
  {
    f32x4 a15[2][2] = {}, a20[2][2] = {};
    for (int ks = 0; ks < 4; ks++) {
      int kb = ks * 32 + (lane >> 4) * 8;
      short8 ah[2], al[2], b5h[2], b5l[2], bth[2], btl[2];
      #pragma unroll
      for (int mt = 0; mt < 2; mt++) {
        int r = brow + mt * 16 + (lane & 15);
        ah[mt] = lds8(sL, r, kb);
        al[mt] = lds8(sL + 16384, r, kb);
      }
      #pragma unroll
      for (int nt = 0; nt < 2; nt++) {
        int c = wcol + nt * 16 + (lane & 15);
        b5h[nt] = *(const short8*)(T5 + c * 128 + kb);
        b5l[nt] = *(const short8*)(T5 + 16384 + c * 128 + kb);
        bth[nt] = lds8(sL, c, kb);
        btl[nt] = lds8(sL + 16384, c, kb);
      }
      #pragma unroll
      for (int mt = 0; mt < 2; mt++)
        #pragma unroll
        for (int nt = 0; nt < 2; nt++) {
          f32x4 x = a15[mt][nt];
          x = __builtin_amdgcn_mfma_f32_16x16x32_bf16(ah[mt], b5h[nt], x, 0, 0, 0);
          x = __builtin_amdgcn_mfma_f32_16x16x32_bf16(al[mt], b5h[nt], x, 0, 0, 0);
          x = __builtin_amdgcn_mfma_f32_16x16x32_bf16(ah[mt], b5l[nt], x, 0, 0, 0);
          a15[mt][nt] = x;
          f32x4 y = a20[mt][nt];
          y = __builtin_amdgcn_mfma_f32_16x16x32_bf16(ah[mt], bth[nt], y, 0, 0, 0);
          y = __builtin_amdgcn_mfma_f32_16x16x32_bf16(al[mt], bth[nt], y, 0, 0, 0);
          y = __builtin_amdgcn_mfma_f32_16x16x32_bf16(ah[mt], btl[nt], y, 0, 0, 0);
          a20[mt][nt] = y;
        }
    }
    #pragma unroll
    for (int mt = 0; mt < 2; mt++)
      #pragma unroll
      for (int nt = 0; nt < 2; nt++)
        #pragma unroll
        for (int r = 0; r < 4; r++) {
          int row = brow + mt * 16 + (lane >> 4) * 4 + r;
          int col = wcol + nt * 16 + (lane & 15);
          int idx = row * 128 + col;
          storeDual(T15, idx, 2.0f * a15[mt][nt][r] - valU(T5, idx));
          storeDual(T20, idx, 2.0f * a20[mt][nt][r] - ((row == col) ? 1.0f : 0.0f));
        }
  }
}

// ---------------- K12: F = G0 + T5 G1 + T10 G2 + T15 G3 + T20 G4 (+trF2) ----------------
__global__ __launch_bounds__(256) void k_bigF(float* __restrict__ ws) {
  __shared__ float red[4];
  float* scal = ws + fSCAL;
  const unsigned short* As[4] = { MS(ws, sT5), MS(ws, sT10), MS(ws, sT15), MS(ws, sT20) };
  const unsigned short* Bs[4] = { MS(ws, sG0 + 1), MS(ws, sG0 + 2), MS(ws, sG0 + 3), MS(ws, sG0 + 4) };
  const unsigned short* G0 = MS(ws, sG0);
  unsigned short* Fm = MS(ws, sF);
  int tid = threadIdx.x, b = blockIdx.x;
  int w = tid >> 6, lane = tid & 63;
  int brow = b * 32, wcol = w * 32;
  f32x4 acc[2][2] = {};
  for (int p = 0; p < 4; p++) {
    const unsigned short* A = As[p];
    const unsigned short* B = Bs[p];
    #pragma unroll
    for (int ks = 0; ks < 4; ks++) {
      int kb = ks * 32 + (lane >> 4) * 8;
      short8 ah[2], al[2], bh[2], bl[2];
      #pragma unroll
      for (int mt = 0; mt < 2; mt++) {
        int r = brow + mt * 16 + (lane & 15);
        ah[mt] = *(const short8*)(A + r * 128 + kb);
        al[mt] = *(const short8*)(A + 16384 + r * 128 + kb);
      }
      #pragma unroll
      for (int nt = 0; nt < 2; nt++) {
        int c = wcol + nt * 16 + (lane & 15);
        bh[nt] = *(const short8*)(B + c * 128 + kb);
        bl[nt] = *(const short8*)(B + 16384 + c * 128 + kb);
      }
      #pragma unroll
      for (int mt = 0; mt < 2; mt++)
        #pragma unroll
        for (int nt = 0; nt < 2; nt++) {
          f32x4 a0 = acc[mt][nt];
          a0 = __builtin_amdgcn_mfma_f32_16x16x32_bf16(ah[mt], bh[nt], a0, 0, 0, 0);
          a0 = __builtin_amdgcn_mfma_f32_16x16x32_bf16(al[mt], bh[nt], a0, 0, 0, 0);
          a0 = __builtin_amdgcn_mfma_f32_16x16x32_bf16(ah[mt], bl[nt], a0, 0, 0, 0);
          acc[mt][nt] = a0;
        }
    }
  }
  float tsum = 0.f;
  #pragma unroll
  for (int mt = 0; mt < 2; mt++)
    #pragma unroll
    for (int nt = 0; nt < 2; nt++)
      #pragma unroll
      for (int r = 0; r < 4; r++) {
        int row = brow + mt * 16 + (lane >> 4) * 4 + r;
        int col = wcol + nt * 16 + (lane & 15);
        int idx = row * 128 + col;
        float g = acc[mt][nt][r] + valU(G0, idx);
        storeDual(Fm, idx, g);
        tsum += g * g;
      }
  #pragma unroll
  for (int off = 32; off > 0; off >>= 1) tsum += __shfl_down(tsum, off);
  if (lane == 0) red[w] = tsum;
  __syncthreads();
  if (tid == 0) scal[72 + b] = red[0] + red[1] + red[2] + red[3];
}

// ---------------- K13: full ZF (LDS) -> B strip -> Bbf ----------------
__global__ __launch_bounds__(256) void k_zfb(float* __restrict__ ws) {
  __shared__ unsigned short sL[32768];
  const unsigned short* Z = MS(ws, sZ);
  const unsigned short* Fm = MS(ws, sF);
  unsigned short* Bbf = (unsigned short*)(ws + fBBF);
  float aeff = ws[fSCAL + 7];
  int tid = threadIdx.x, b = blockIdx.x;
  int w = tid >> 6, lane = tid & 63;
  int wcol = w * 32, brow = b * 32;
  {
    f32x4 acc[8][2] = {};
    for (int ks = 0; ks < 4; ks++) {
      int kb = ks * 32 + (lane >> 4) * 8;
      short8 bh[2], bl[2];
      #pragma unroll
      for (int nt = 0; nt < 2; nt++) {
        int c = wcol + nt * 16 + (lane & 15);
        bh[nt] = *(const short8*)(Fm + c * 128 + kb);
        bl[nt] = *(const short8*)(Fm + 16384 + c * 128 + kb);
      }
      #pragma unroll
      for (int mt = 0; mt < 8; mt++) {
        int r = mt * 16 + (lane & 15);
        short8 ah = *(const short8*)(Z + r * 128 + kb);
        short8 al = *(const short8*)(Z + 16384 + r * 128 + kb);
        #pragma unroll
        for (int nt = 0; nt < 2; nt++) {
          f32x4 a0 = acc[mt][nt];
          a0 = __builtin_amdgcn_mfma_f32_16x16x32_bf16(ah, bh[nt], a0, 0, 0, 0);
          a0 = __builtin_amdgcn_mfma_f32_16x16x32_bf16(al, bh[nt], a0, 0, 0, 0);
          a0 = __builtin_amdgcn_mfma_f32_16x16x32_bf16(ah, bl[nt], a0, 0, 0, 0);
          acc[mt][nt] = a0;
        }
      }
    }
    #pragma unroll
    for (int mt = 0; mt < 8; mt++)
      #pragma unroll
      for (int nt = 0; nt < 2; nt++)
        #pragma unroll
        for (int r = 0; r < 4; r++) {
          int row = mt * 16 + (lane >> 4) * 4 + r;
          int col = wcol + nt * 16 + (lane & 15);
          ldsPutDual(sL, row, col, acc[mt][nt][r]);
        }
  }
  __syncthreads();
  {
    f32x4 acc[2][2] = {};
    for (int ks = 0; ks < 4; ks++) {
      int kb = ks * 32 + (lane >> 4) * 8;
      short8 ah[2], al[2], bh[2], bl[2];
      #pragma unroll
      for (int mt = 0; mt < 2; mt++) {
        int r = brow + mt * 16 + (lane & 15);
        ah[mt] = lds8(sL, r, kb);
        al[mt] = lds8(sL + 16384, r, kb);
      }
      #pragma unroll
      for (int nt = 0; nt < 2; nt++) {
        int c = wcol + nt * 16 + (lane & 15);
        bh[nt] = *(const short8*)(Z + c * 128 + kb);
        bl[nt] = *(const short8*)(Z + 16384 + c * 128 + kb);
      }
      #pragma unroll
      for (int mt = 0; mt < 2; mt++)
        #pragma unroll
        for (int nt = 0; nt < 2; nt++) {
          f32x4 a0 = acc[mt][nt];
          a0 = __builtin_amdgcn_mfma_f32_16x16x32_bf16(ah[mt], bh[nt], a0, 0, 0, 0);
          a0 = __builtin_amdgcn_mfma_f32_16x16x32_bf16(al[mt], bh[nt], a0, 0, 0, 0);
          a0 = __builtin_amdgcn_mfma_f32_16x16x32_bf16(ah[mt], bl[nt], a0, 0, 0, 0);
          acc[mt][nt] = a0;
        }
    }
    #pragma unroll
    for (int mt = 0; mt < 2; mt++)
      #pragma unroll
      for (int nt = 0; nt < 2; nt++)
        #pragma unroll
        for (int r = 0; r < 4; r++) {
          int row = brow + mt * 16 + (lane >> 4) * 4 + r;
          int col = wcol + nt * 16 + (lane & 15);
          Bbf[row * 128 + col] = f2bf(acc[mt][nt][r] * aeff);
        }
  }
}

// ---------------- K14: V = test - mean; U = V*B; q; blk0: log_div ----------------
__global__ __launch_bounds__(256) void k_latent(const float* __restrict__ test, float* __restrict__ ws) {
  __shared__ unsigned short vh[16384];
  __shared__ float qs[128];
  int blk = blockIdx.x, tid = threadIdx.x;
  if (blk == 0 && tid == 0) {
    float* scal = ws + fSCAL;
    float trF2 = fmaxf(scal[72] + scal[73] + scal[74] + scal[75], 1e-30f);
    scal[0] = 0.5f * (128.0f * 1.8378770664093453f + 0.5f * logf(trF2));
  }
  const float* tb = test + blk * 128 * D;
  unsigned short* Vbf = (unsigned short*)(ws + fV);
  if (tid < 128) qs[tid] = 0.f;
  for (int idx = tid; idx < 16384; idx += 256) {
    int r = idx >> 7, c = idx & 127;
    float v = tb[idx] - ws[fMEAN + c];
    unsigned short h = f2bf(v);
    unsigned byte = ((unsigned)(r * 256 + c * 2)) ^ (((unsigned)(r & 7)) << 4);
    *(unsigned short*)((char*)vh + byte) = h;
    Vbf[blk * 16384 + idx] = h;
  }
  __syncthreads();
  int w = tid >> 6, lane = tid & 63;
  int wr = (w >> 1) * 64, wc = (w & 1) * 64;
  const unsigned short* Bbf = (const unsigned short*)(ws + fBBF);
  f32x4 acc[4][4] = {};
  for (int ks = 0; ks < 4; ks++) {
    int kb = ks * 32 + (lane >> 4) * 8;
    short8 af[4], bfv[4];
    #pragma unroll
    for (int mt = 0; mt < 4; mt++) {
      int r = wr + mt * 16 + (lane & 15);
      unsigned byte = ((unsigned)(r * 256 + kb * 2)) ^ (((unsigned)(r & 7)) << 4);
      af[mt] = *(short8*)((char*)vh + byte);
    }
    #pragma unroll
    for (int nt = 0; nt < 4; nt++) {
      int c = wc + nt * 16 + (lane & 15);
      bfv[nt] = *(const short8*)(Bbf + c * 128 + kb);
    }
    #pragma unroll
    for (int mt = 0; mt < 4; mt++)
      #pragma unroll
      for (int nt = 0; nt < 4; nt++)
        acc[mt][nt] = __builtin_amdgcn_mfma_f32_16x16x32_bf16(af[mt], bfv[nt], acc[mt][nt], 0, 0, 0);
  }
  unsigned short* Ubf = (unsigned short*)(ws + fU);
  #pragma unroll
  for (int mt = 0; mt < 4; mt++)
    #pragma unroll
    for (int nt = 0; nt < 4; nt++)
      #pragma unroll
      for (int r = 0; r < 4; r++) {
        int row = wr + mt * 16 + (lane >> 4) * 4 + r;
        int col = wc + nt * 16 + (lane & 15);
        Ubf[(blk * 128 + row) * 128 + col] = f2bf(acc[mt][nt][r]);
      }
  #pragma unroll
  for (int mt = 0; mt < 4; mt++)
    #pragma unroll
    for (int r = 0; r < 4; r++) {
      int row = wr + mt * 16 + (lane >> 4) * 4 + r;
      float p = 0.f;
      #pragma unroll
      for (int nt = 0; nt < 4; nt++) {
        int col = wc + nt * 16 + (lane & 15);
        unsigned byte = ((unsigned)(row * 256 + col * 2)) ^ (((unsigned)(row & 7)) << 4);
        p += bf2f(f2bf(acc[mt][nt][r])) * bf2f(*(unsigned short*)((char*)vh + byte));
      }
      p += __shfl_xor(p, 1, 16);
      p += __shfl_xor(p, 2, 16);
      p += __shfl_xor(p, 4, 16);
      p += __shfl_xor(p, 8, 16);
      if ((lane & 15) == 0) atomicAdd(&qs[row], p);  // exactly 2 adds/row
    }
  __syncthreads();
  if (tid < 128) ws[fQ + blk * 128 + tid] = qs[tid];
}

// ---------------- K15: out = 2 U V^T - q_i - q_j - log_div ----------------
__global__ __launch_bounds__(256) void k_pair(const float* __restrict__ ws, float* __restrict__ out) {
  __shared__ float qi[128];
  __shared__ float qj[128];
  __shared__ float sld;
  int bi = blockIdx.x, bj = blockIdx.y, tid = threadIdx.x;
  if (tid < 128) qi[tid] = ws[fQ + bi * 128 + tid];
  else qj[tid - 128] = ws[fQ + bj * 128 + (tid - 128)];
  if (tid == 0) sld = ws[fSCAL + 0];
  __syncthreads();
  int w = tid >> 6, lane = tid & 63;
  int wr = (w >> 1) * 64, wc = (w & 1) * 64;
  const unsigned short* Ubf = (const unsigned short*)(ws + fU);
  const unsigned short* Vbf = (const unsigned short*)(ws + fV);
  f32x4 acc[4][4] = {};
  for (int ks = 0; ks < 4; ks++) {
    int kb = ks * 32 + (lane >> 4) * 8;
    short8 af[4], bfv[4];
    #pragma unroll
    for (int mt = 0; mt < 4; mt++) {
      int r = bi * 128 + wr + mt * 16 + (lane & 15);
      af[mt] = *(const short8*)(Ubf + r * 128 + kb);
    }
    #pragma unroll
    for (int nt = 0; nt < 4; nt++) {
      int c = bj * 128 + wc + nt * 16 + (lane & 15);
      bfv[nt] = *(const short8*)(Vbf + c * 128 + kb);
    }
    #pragma unroll
    for (int mt = 0; mt < 4; mt++)
      #pragma unroll
      for (int nt = 0; nt < 4; nt++)
        acc[mt][nt] = __builtin_amdgcn_mfma_f32_16x16x32_bf16(af[mt], bfv[nt], acc[mt][nt], 0, 0, 0);
  }
  float ld = sld;
  #pragma unroll
  for (int mt = 0; mt < 4; mt++)
    #pragma unroll
    for (int nt = 0; nt < 4; nt++)
      #pragma unroll
      for (int r = 0; r < 4; r++) {
        int row = wr + mt * 16 + (lane >> 4) * 4 + r;
        int col = wc + nt * 16 + (lane & 15);
        float g = acc[mt][nt][r];
        out[(size_t)(bi * 128 + row) * MTEST + (bj * 128 + col)] =
          2.0f * g - qi[row] - qj[col] - ld;
      }
}

extern "C" void kernel_launch(void* const* d_in, const int* in_sizes, int n_in,
                              void* d_out, int out_size, void* d_ws, size_t ws_size,
                              hipStream_t stream) {
  (void)in_sizes; (void)n_in; (void)out_size; (void)ws_size;
  const float* X = (const float*)d_in[0];
  const float* test = (const float*)d_in[1];
  float* out = (float*)d_out;
  float* ws = (float*)d_ws;

  k_gt_partial<<<64, 256, 0, stream>>>(X, ws);
  k_reduce<<<64, 256, 0, stream>>>(ws);
  k_sbp<<<4, 256, 0, stream>>>(ws);        // SB + P
  k_p234<<<4, 256, 0, stream>>>(ws);       // P2 full -> P3,P4 (+trP8)
  k_z<<<4, 256, 0, stream>>>(ws);          // Z
  k_msb<<<4, 256, 0, stream>>>(ws);        // ZSB full -> Mm
  k_c24<<<4, 256, 0, stream>>>(ws);        // C2 full -> trM8
  k_xh_t2<<<16, 256, 0, stream>>>(ws);     // XH, T2
  k_t34<<<8, 256, 0, stream>>>(ws);        // T3 | T4
  k_t5g<<<20, 256, 0, stream>>>(ws);       // T5 | G0..G4
  k_t101520<<<4, 256, 0, stream>>>(ws);    // T10 full -> T15, T20
  k_bigF<<<4, 256, 0, stream>>>(ws);       // F (+trF2)
  k_zfb<<<4, 256, 0, stream>>>(ws);        // ZF full -> Bbf
  k_latent<<<64, 256, 0, stream>>>(test, ws);
  k_pair<<<dim3(64, 64), 256, 0, stream>>>(ws, out);
}

// Round 11
// 265.358 us; speedup vs baseline: 1.1323x; 1.1323x over previous
//
#include <hip/hip_runtime.h>
#include <math.h>

// PLDA pairwise scorer, eigendecomposition-free, all-symmetric formulation.
// Z = S_wn^{-1/2} via degree-6 Chebyshev in P = S_wn - I; M = Z*SB*Z;
// F = f0(inv_s*M) via degree-24 bivariate Chebyshev
// (F = G0 + T5*G1 + T10*G2 + T15*G3 + T20*G4); B = (63/64)*inv_s*Z*F*Z.
// out = 2 v_i^T B v_j - q_i - q_j - log_div.
// Zero-redundancy strip-chaining: block b keeps its 32-row strip of an
// intermediate product in LDS (dual bf16) as the A-operand of the next
// product; every B-operand is a matrix completed in an earlier launch.
// 15 dispatches.

#define D 128
#define NCLS 256
#define NPC 64
#define MTEST 8192
#define COUNT (NCLS*NPC)

// ws float-offset layout
#define fMC    0                      // McT bf16 [128][256]
#define fMEAN  16384                  // 128 f32
#define fSCAL  16640                  // scalars (256 f32)
#define fMAT   32768                  // 25 dual-plane matrices x 16384 fl
#define fSWRAW 442368                 // 16384 f32 Gram sum
#define fPART  458752                 // 64*16384 f32 (dead after k_reduce)
#define fU     458752
#define fV     983040
#define fQ     1507328
#define fBBF   1515520

// matrix slots
#define sP   0
#define sSB  1
#define sP2  2
#define sP3  3
#define sP4  4
#define sZ   5
#define sMm  7
#define sC2  8
#define sXH  10
#define sT2  11
#define sT3  12
#define sT4  13
#define sT5  14
#define sT10 15
#define sT15 16
#define sT20 17
#define sG0  18   // G0..G4 = 18..22
#define sF   23

using short8 = __attribute__((ext_vector_type(8))) short;
using f32x4  = __attribute__((ext_vector_type(4))) float;

__device__ inline unsigned short f2bf(float f) {
  unsigned u = __float_as_uint(f);
  unsigned r = u + 0x7FFFu + ((u >> 16) & 1u);
  return (unsigned short)(r >> 16);
}
__device__ inline float bf2f(unsigned short h) {
  return __uint_as_float(((unsigned)h) << 16);
}
__device__ inline float valU(const unsigned short* m, int idx) {
  return bf2f(m[idx]) + bf2f(m[idx + 16384]);
}
__device__ inline void storeDual(unsigned short* m, int idx, float g) {
  unsigned short hb = f2bf(g);
  m[idx] = hb;
  m[16384 + idx] = f2bf(g - bf2f(hb));
}
__device__ inline unsigned short* MS(float* ws, int m) {
  return (unsigned short*)(ws + fMAT) + (size_t)m * 32768;
}
// 32-row LDS strip, dual plane (4096-ushort stride), XOR-swizzled rows
__device__ inline short8 st8(const unsigned short* L, int rloc, int colk) {
  unsigned u = ((unsigned)(rloc * 128 + colk)) ^ (((unsigned)(rloc & 7)) << 3);
  return *(const short8*)(L + u);
}
__device__ inline float stValU(const unsigned short* L, int rloc, int col) {
  unsigned u = ((unsigned)(rloc * 128 + col)) ^ (((unsigned)(rloc & 7)) << 3);
  return bf2f(L[u]) + bf2f(L[4096 + u]);
}
__device__ inline void stPutDual(unsigned short* L, int rloc, int col, float g) {
  unsigned u = ((unsigned)(rloc * 128 + col)) ^ (((unsigned)(rloc & 7)) << 3);
  unsigned short hb = f2bf(g);
  L[u] = hb;
  L[4096 + u] = f2bf(g - bf2f(hb));
}

// ---------------- generic strip matmul: C = alpha*(A x B) [+ beta*E1] [+ delta*I]
__device__ float mm_core(const unsigned short* A, const unsigned short* B,
                         unsigned short* C, const unsigned short* E1,
                         float alpha, float beta, float delta, int brow,
                         unsigned short* outBf, float aeff2) {
  int tid = threadIdx.x;
  int w = tid >> 6, lane = tid & 63;
  int wcol = w * 32;
  f32x4 acc[2][2] = {};
  #pragma unroll
  for (int ks = 0; ks < 4; ks++) {
    int kb = ks * 32 + (lane >> 4) * 8;
    short8 ah[2], al[2], bh[2], bl[2];
    #pragma unroll
    for (int mt = 0; mt < 2; mt++) {
      int r = brow + mt * 16 + (lane & 15);
      ah[mt] = *(const short8*)(A + r * 128 + kb);
      al[mt] = *(const short8*)(A + 16384 + r * 128 + kb);
    }
    #pragma unroll
    for (int nt = 0; nt < 2; nt++) {
      int c = wcol + nt * 16 + (lane & 15);
      bh[nt] = *(const short8*)(B + c * 128 + kb);
      bl[nt] = *(const short8*)(B + 16384 + c * 128 + kb);
    }
    #pragma unroll
    for (int mt = 0; mt < 2; mt++)
      #pragma unroll
      for (int nt = 0; nt < 2; nt++) {
        f32x4 a0 = acc[mt][nt];
        a0 = __builtin_amdgcn_mfma_f32_16x16x32_bf16(ah[mt], bh[nt], a0, 0, 0, 0);
        a0 = __builtin_amdgcn_mfma_f32_16x16x32_bf16(al[mt], bh[nt], a0, 0, 0, 0);
        a0 = __builtin_amdgcn_mfma_f32_16x16x32_bf16(ah[mt], bl[nt], a0, 0, 0, 0);
        acc[mt][nt] = a0;
      }
  }
  float tsum = 0.f;
  #pragma unroll
  for (int mt = 0; mt < 2; mt++)
    #pragma unroll
    for (int nt = 0; nt < 2; nt++)
      #pragma unroll
      for (int r = 0; r < 4; r++) {
        int row = brow + mt * 16 + (lane >> 4) * 4 + r;
        int col = wcol + nt * 16 + (lane & 15);
        int idx = row * 128 + col;
        float g = acc[mt][nt][r] * alpha;
        if (E1) g += beta * valU(E1, idx);
        if (row == col) g += delta;
        if (outBf) outBf[idx] = f2bf(g * aeff2);
        else storeDual(C, idx, g);
        tsum += g * g;
      }
  return tsum;
}

// ---------------- K1: Gram partials + class means ----------------
__global__ __launch_bounds__(256) void k_gt_partial(const float* __restrict__ X, float* __restrict__ ws) {
  __shared__ unsigned short xt[128 * 256]; // 64 KB
  int b = blockIdx.x, tid = threadIdx.x;
  const float* Xc = X + b * 256 * D;
  for (int idx = tid; idx < 256 * D; idx += 256) {
    int s = idx >> 7, d = idx & 127;
    unsigned byte = ((unsigned)(d * 512 + s * 2)) ^ (((unsigned)(d & 7)) << 4);
    *(unsigned short*)((char*)xt + byte) = f2bf(Xc[idx]);
  }
  {
    int d = tid & 127;
    for (int cc = (tid >> 7); cc < 4; cc += 2) {
      const float* p = Xc + cc * 64 * D + d;
      float s = 0.f;
      #pragma unroll
      for (int n = 0; n < 64; n++) s += p[n * D];
      ((unsigned short*)ws)[d * 256 + (b * 4 + cc)] = f2bf(s * (1.0f / 64.0f));
    }
  }
  __syncthreads();
  int w = tid >> 6, lane = tid & 63;
  int wr = (w >> 1) * 64, wc = (w & 1) * 64;
  f32x4 acc[4][4] = {};
  for (int ks = 0; ks < 8; ks++) {
    int kb = ks * 32 + (lane >> 4) * 8;
    short8 af[4];
    #pragma unroll
    for (int mt = 0; mt < 4; mt++) {
      int r = wr + mt * 16 + (lane & 15);
      unsigned byte = ((unsigned)(r * 512 + kb * 2)) ^ (((unsigned)(r & 7)) << 4);
      af[mt] = *(short8*)((char*)xt + byte);
    }
    #pragma unroll
    for (int nt = 0; nt < 4; nt++) {
      int c = wc + nt * 16 + (lane & 15);
      unsigned byte = ((unsigned)(c * 512 + kb * 2)) ^ (((unsigned)(c & 7)) << 4);
      short8 bfr = *(short8*)((char*)xt + byte);
      #pragma unroll
      for (int mt = 0; mt < 4; mt++)
        acc[mt][nt] = __builtin_amdgcn_mfma_f32_16x16x32_bf16(af[mt], bfr, acc[mt][nt], 0, 0, 0);
    }
  }
  float* outp = ws + fPART + b * 16384;
  #pragma unroll
  for (int mt = 0; mt < 4; mt++)
    #pragma unroll
    for (int nt = 0; nt < 4; nt++)
      #pragma unroll
      for (int r = 0; r < 4; r++) {
        int row = wr + mt * 16 + (lane >> 4) * 4 + r;
        int col = wc + nt * 16 + (lane & 15);
        outp[row * 128 + col] = acc[mt][nt][r];
      }
}

// ---------------- K2: reduce partials; blk0: mean; blk1: inv_s ----------------
__global__ void k_reduce(float* __restrict__ ws) {
  __shared__ float red2[4];
  int tid = threadIdx.x;
  int idx = blockIdx.x * 256 + tid;
  const float* part = ws + fPART;
  float s = 0.f;
  #pragma unroll 8
  for (int p = 0; p < 64; p++) s += part[p * 16384 + idx];
  ws[fSWRAW + idx] = s;
  if (blockIdx.x == 0 && tid < 128) {
    const unsigned short* McT = (const unsigned short*)ws;
    float m = 0.f;
    for (int k = 0; k < 256; k++) m += bf2f(McT[tid * 256 + k]);
    ws[fMEAN + tid] = m * (1.0f / 256.0f);
  }
  if (blockIdx.x == 1) {
    float v = 0.f;
    if (tid < 128) {
      float gdd = 0.f;
      for (int p = 0; p < 64; p++) gdd += part[p * 16384 + tid * 129];
      const unsigned short* McT = (const unsigned short*)ws;
      float nrm = 0.f;
      for (int k = 0; k < 256; k++) { float x = bf2f(McT[tid * 256 + k]); nrm += x * x; }
      v = gdd * (1.0f / COUNT) - nrm * (1.0f / 256.0f);
    }
    #pragma unroll
    for (int off = 32; off > 0; off >>= 1) v += __shfl_down(v, off);
    if ((tid & 63) == 0) red2[tid >> 6] = v;
    __syncthreads();
    if (tid == 0) {
      float inv_s = 128.0f / (red2[0] + red2[1] + red2[2] + red2[3]);
      ws[fSCAL + 1] = inv_s;
      ws[fSCAL + 7] = 0.984375f * inv_s;
    }
  }
}

// ---------------- K3: SB strip (K=256 MFMA) + P = S_wn - I strip ----------------
__global__ __launch_bounds__(256) void k_sbp(float* __restrict__ ws) {
  const unsigned short* Mc = (const unsigned short*)ws;
  const float* mv = ws + fMEAN;
  const float* swraw = ws + fSWRAW;
  float inv_s = ws[fSCAL + 1];
  unsigned short* SB = MS(ws, sSB);
  unsigned short* P = MS(ws, sP);
  int tid = threadIdx.x, b = blockIdx.x;
  int w = tid >> 6, lane = tid & 63;
  int brow = b * 32, wcol = w * 32;
  f32x4 acc[2][2] = {};
  for (int ks = 0; ks < 8; ks++) {
    int kb = ks * 32 + (lane >> 4) * 8;
    short8 af[2], bfv[2];
    #pragma unroll
    for (int mt = 0; mt < 2; mt++) {
      int r = brow + mt * 16 + (lane & 15);
      af[mt] = *(const short8*)(Mc + r * 256 + kb);
    }
    #pragma unroll
    for (int nt = 0; nt < 2; nt++) {
      int c = wcol + nt * 16 + (lane & 15);
      bfv[nt] = *(const short8*)(Mc + c * 256 + kb);
    }
    #pragma unroll
    for (int mt = 0; mt < 2; mt++)
      #pragma unroll
      for (int nt = 0; nt < 2; nt++)
        acc[mt][nt] = __builtin_amdgcn_mfma_f32_16x16x32_bf16(af[mt], bfv[nt], acc[mt][nt], 0, 0, 0);
  }
  #pragma unroll
  for (int mt = 0; mt < 2; mt++)
    #pragma unroll
    for (int nt = 0; nt < 2; nt++)
      #pragma unroll
      for (int r = 0; r < 4; r++) {
        int row = brow + mt * 16 + (lane >> 4) * 4 + r;
        int col = wcol + nt * 16 + (lane & 15);
        int idx = row * 128 + col;
        float g = acc[mt][nt][r] * (1.0f / 256.0f) - mv[row] * mv[col];
        storeDual(SB, idx, g);
        float s = (swraw[idx] * (1.0f / COUNT) - g - mv[row] * mv[col]) * inv_s;
        storeDual(P, idx, s - ((row == col) ? 1.0f : 0.0f));
      }
}

// ---------------- K4: strips P2 -> P3 -> P4 (+tr P^8) ----------------
__global__ __launch_bounds__(256) void k_pows(float* __restrict__ ws) {
  __shared__ unsigned short sA[8192]; // strip dual 16 KB
  __shared__ unsigned short sB[8192];
  __shared__ float red[4];
  float* scal = ws + fSCAL;
  const unsigned short* P = MS(ws, sP);
  unsigned short* P2 = MS(ws, sP2);
  unsigned short* P3 = MS(ws, sP3);
  unsigned short* P4 = MS(ws, sP4);
  int tid = threadIdx.x, b = blockIdx.x;
  int w = tid >> 6, lane = tid & 63;
  int brow = b * 32, wcol = w * 32;
  // phase1: P2 strip = P[rows]*P
  {
    f32x4 acc[2][2] = {};
    #pragma unroll
    for (int ks = 0; ks < 4; ks++) {
      int kb = ks * 32 + (lane >> 4) * 8;
      short8 ah[2], al[2], bh[2], bl[2];
      #pragma unroll
      for (int mt = 0; mt < 2; mt++) {
        int r = brow + mt * 16 + (lane & 15);
        ah[mt] = *(const short8*)(P + r * 128 + kb);
        al[mt] = *(const short8*)(P + 16384 + r * 128 + kb);
      }
      #pragma unroll
      for (int nt = 0; nt < 2; nt++) {
        int c = wcol + nt * 16 + (lane & 15);
        bh[nt] = *(const short8*)(P + c * 128 + kb);
        bl[nt] = *(const short8*)(P + 16384 + c * 128 + kb);
      }
      #pragma unroll
      for (int mt = 0; mt < 2; mt++)
        #pragma unroll
        for (int nt = 0; nt < 2; nt++) {
          f32x4 a0 = acc[mt][nt];
          a0 = __builtin_amdgcn_mfma_f32_16x16x32_bf16(ah[mt], bh[nt], a0, 0, 0, 0);
          a0 = __builtin_amdgcn_mfma_f32_16x16x32_bf16(al[mt], bh[nt], a0, 0, 0, 0);
          a0 = __builtin_amdgcn_mfma_f32_16x16x32_bf16(ah[mt], bl[nt], a0, 0, 0, 0);
          acc[mt][nt] = a0;
        }
    }
    #pragma unroll
    for (int mt = 0; mt < 2; mt++)
      #pragma unroll
      for (int nt = 0; nt < 2; nt++)
        #pragma unroll
        for (int r = 0; r < 4; r++) {
          int rloc = mt * 16 + (lane >> 4) * 4 + r;
          int col = wcol + nt * 16 + (lane & 15);
          float g = acc[mt][nt][r];
          stPutDual(sA, rloc, col, g);
          storeDual(P2, (brow + rloc) * 128 + col, g);
        }
  }
  __syncthreads();
  // phase2: P3 strip = sA*P
  {
    f32x4 acc[2][2] = {};
    #pragma unroll
    for (int ks = 0; ks < 4; ks++) {
      int kb = ks * 32 + (lane >> 4) * 8;
      short8 ah[2], al[2], bh[2], bl[2];
      #pragma unroll
      for (int mt = 0; mt < 2; mt++) {
        int rloc = mt * 16 + (lane & 15);
        ah[mt] = st8(sA, rloc, kb);
        al[mt] = st8(sA + 4096, rloc, kb);
      }
      #pragma unroll
      for (int nt = 0; nt < 2; nt++) {
        int c = wcol + nt * 16 + (lane & 15);
        bh[nt] = *(const short8*)(P + c * 128 + kb);
        bl[nt] = *(const short8*)(P + 16384 + c * 128 + kb);
      }
      #pragma unroll
      for (int mt = 0; mt < 2; mt++)
        #pragma unroll
        for (int nt = 0; nt < 2; nt++) {
          f32x4 a0 = acc[mt][nt];
          a0 = __builtin_amdgcn_mfma_f32_16x16x32_bf16(ah[mt], bh[nt], a0, 0, 0, 0);
          a0 = __builtin_amdgcn_mfma_f32_16x16x32_bf16(al[mt], bh[nt], a0, 0, 0, 0);
          a0 = __builtin_amdgcn_mfma_f32_16x16x32_bf16(ah[mt], bl[nt], a0, 0, 0, 0);
          acc[mt][nt] = a0;
        }
    }
    #pragma unroll
    for (int mt = 0; mt < 2; mt++)
      #pragma unroll
      for (int nt = 0; nt < 2; nt++)
        #pragma unroll
        for (int r = 0; r < 4; r++) {
          int rloc = mt * 16 + (lane >> 4) * 4 + r;
          int col = wcol + nt * 16 + (lane & 15);
          float g = acc[mt][nt][r];
          stPutDual(sB, rloc, col, g);
          storeDual(P3, (brow + rloc) * 128 + col, g);
        }
  }
  __syncthreads();
  // phase3: P4 strip = sB*P (+||P4||^2 partial)
  float tsum = 0.f;
  {
    f32x4 acc[2][2] = {};
    #pragma unroll
    for (int ks = 0; ks < 4; ks++) {
      int kb = ks * 32 + (lane >> 4) * 8;
      short8 ah[2], al[2], bh[2], bl[2];
      #pragma unroll
      for (int mt = 0; mt < 2; mt++) {
        int rloc = mt * 16 + (lane & 15);
        ah[mt] = st8(sB, rloc, kb);
        al[mt] = st8(sB + 4096, rloc, kb);
      }
      #pragma unroll
      for (int nt = 0; nt < 2; nt++) {
        int c = wcol + nt * 16 + (lane & 15);
        bh[nt] = *(const short8*)(P + c * 128 + kb);
        bl[nt] = *(const short8*)(P + 16384 + c * 128 + kb);
      }
      #pragma unroll
      for (int mt = 0; mt < 2; mt++)
        #pragma unroll
        for (int nt = 0; nt < 2; nt++) {
          f32x4 a0 = acc[mt][nt];
          a0 = __builtin_amdgcn_mfma_f32_16x16x32_bf16(ah[mt], bh[nt], a0, 0, 0, 0);
          a0 = __builtin_amdgcn_mfma_f32_16x16x32_bf16(al[mt], bh[nt], a0, 0, 0, 0);
          a0 = __builtin_amdgcn_mfma_f32_16x16x32_bf16(ah[mt], bl[nt], a0, 0, 0, 0);
          acc[mt][nt] = a0;
        }
    }
    #pragma unroll
    for (int mt = 0; mt < 2; mt++)
      #pragma unroll
      for (int nt = 0; nt < 2; nt++)
        #pragma unroll
        for (int r = 0; r < 4; r++) {
          int rloc = mt * 16 + (lane >> 4) * 4 + r;
          int col = wcol + nt * 16 + (lane & 15);
          float g = acc[mt][nt][r];
          storeDual(P4, (brow + rloc) * 128 + col, g);
          tsum += g * g;
        }
  }
  #pragma unroll
  for (int off = 32; off > 0; off >>= 1) tsum += __shfl_down(tsum, off);
  if (lane == 0) red[w] = tsum;
  __syncthreads();
  if (tid == 0) scal[60 + b] = red[0] + red[1] + red[2] + red[3];
}

// ---------------- K5: P5,P6 in-reg + Z = sum beta_k P^k ----------------
__global__ __launch_bounds__(256) void k_z(float* __restrict__ ws) {
  __shared__ float cj[7];
  __shared__ float bt[7];
  float* scal = ws + fSCAL;
  const unsigned short *P = MS(ws, sP), *P2 = MS(ws, sP2),
    *P3 = MS(ws, sP3), *P4 = MS(ws, sP4);
  unsigned short* Z = MS(ws, sZ);
  int tid = threadIdx.x, b = blockIdx.x;
  float trP8 = scal[60] + scal[61] + scal[62] + scal[63];
  float a = 1.05f * sqrtf(sqrtf(sqrtf(fmaxf(trP8, 1e-30f))));
  a = fminf(a, 0.95f);
  if (tid < 7) {
    const float PI = 3.14159265358979f;
    float s = 0.f;
    for (int i = 0; i < 64; i++) {
      float th = (i + 0.5f) * (PI / 64.0f);
      float x = cosf(th);
      s += (1.0f / sqrtf(1.0f + a * x)) * cosf((float)tid * th);
    }
    cj[tid] = s * (2.0f / 64.0f);
  }
  __syncthreads();
  if (tid == 0) {
    float c0h = 0.5f * cj[0];
    float m0 = c0h - cj[2] + cj[4] - cj[6];
    float m1 = cj[1] - 3.0f * cj[3] + 5.0f * cj[5];
    float m2 = 2.0f * cj[2] - 8.0f * cj[4] + 18.0f * cj[6];
    float m3 = 4.0f * cj[3] - 20.0f * cj[5];
    float m4 = 8.0f * cj[4] - 48.0f * cj[6];
    float m5 = 16.0f * cj[5];
    float m6 = 32.0f * cj[6];
    float ia = 1.0f / a, p = 1.f;
    bt[0] = m0;
    p *= ia; bt[1] = m1 * p;
    p *= ia; bt[2] = m2 * p;
    p *= ia; bt[3] = m3 * p;
    p *= ia; bt[4] = m4 * p;
    p *= ia; bt[5] = m5 * p;
    p *= ia; bt[6] = m6 * p;
  }
  __syncthreads();
  int w = tid >> 6, lane = tid & 63;
  int brow = b * 32, wcol = w * 32;
  f32x4 a5[2][2] = {}, a6[2][2] = {};
  #pragma unroll
  for (int ks = 0; ks < 4; ks++) {
    int kb = ks * 32 + (lane >> 4) * 8;
    short8 ah[2], al[2], b5h[2], b5l[2], b6h[2], b6l[2];
    #pragma unroll
    for (int mt = 0; mt < 2; mt++) {
      int r = brow + mt * 16 + (lane & 15);
      ah[mt] = *(const short8*)(P4 + r * 128 + kb);
      al[mt] = *(const short8*)(P4 + 16384 + r * 128 + kb);
    }
    #pragma unroll
    for (int nt = 0; nt < 2; nt++) {
      int c = wcol + nt * 16 + (lane & 15);
      b5h[nt] = *(const short8*)(P + c * 128 + kb);
      b5l[nt] = *(const short8*)(P + 16384 + c * 128 + kb);
      b6h[nt] = *(const short8*)(P2 + c * 128 + kb);
      b6l[nt] = *(const short8*)(P2 + 16384 + c * 128 + kb);
    }
    #pragma unroll
    for (int mt = 0; mt < 2; mt++)
      #pragma unroll
      for (int nt = 0; nt < 2; nt++) {
        f32x4 x5 = a5[mt][nt];
        x5 = __builtin_amdgcn_mfma_f32_16x16x32_bf16(ah[mt], b5h[nt], x5, 0, 0, 0);
        x5 = __builtin_amdgcn_mfma_f32_16x16x32_bf16(al[mt], b5h[nt], x5, 0, 0, 0);
        x5 = __builtin_amdgcn_mfma_f32_16x16x32_bf16(ah[mt], b5l[nt], x5, 0, 0, 0);
        a5[mt][nt] = x5;
        f32x4 x6 = a6[mt][nt];
        x6 = __builtin_amdgcn_mfma_f32_16x16x32_bf16(ah[mt], b6h[nt], x6, 0, 0, 0);
        x6 = __builtin_amdgcn_mfma_f32_16x16x32_bf16(al[mt], b6h[nt], x6, 0, 0, 0);
        x6 = __builtin_amdgcn_mfma_f32_16x16x32_bf16(ah[mt], b6l[nt], x6, 0, 0, 0);
        a6[mt][nt] = x6;
      }
  }
  #pragma unroll
  for (int mt = 0; mt < 2; mt++)
    #pragma unroll
    for (int nt = 0; nt < 2; nt++)
      #pragma unroll
      for (int r = 0; r < 4; r++) {
        int row = brow + mt * 16 + (lane >> 4) * 4 + r;
        int col = wcol + nt * 16 + (lane & 15);
        int idx = row * 128 + col;
        float dg = (row == col) ? 1.0f : 0.0f;
        float z = bt[0] * dg + bt[1] * valU(P, idx) + bt[2] * valU(P2, idx) +
                  bt[3] * valU(P3, idx) + bt[4] * valU(P4, idx) +
                  bt[5] * a5[mt][nt][r] + bt[6] * a6[mt][nt][r];
        storeDual(Z, idx, z);
      }
}

// ---------------- K6: M1 strip (LDS) -> Mm strip ----------------
__global__ __launch_bounds__(256) void k_m(float* __restrict__ ws) {
  __shared__ unsigned short sA[8192];
  const unsigned short* Z = MS(ws, sZ);
  const unsigned short* SB = MS(ws, sSB);
  unsigned short* Mm = MS(ws, sMm);
  int tid = threadIdx.x, b = blockIdx.x;
  int w = tid >> 6, lane = tid & 63;
  int brow = b * 32, wcol = w * 32;
  // phase1: M1 strip = Z[rows]*SB (LDS only)
  {
    f32x4 acc[2][2] = {};
    #pragma unroll
    for (int ks = 0; ks < 4; ks++) {
      int kb = ks * 32 + (lane >> 4) * 8;
      short8 ah[2], al[2], bh[2], bl[2];
      #pragma unroll
      for (int mt = 0; mt < 2; mt++) {
        int r = brow + mt * 16 + (lane & 15);
        ah[mt] = *(const short8*)(Z + r * 128 + kb);
        al[mt] = *(const short8*)(Z + 16384 + r * 128 + kb);
      }
      #pragma unroll
      for (int nt = 0; nt < 2; nt++) {
        int c = wcol + nt * 16 + (lane & 15);
        bh[nt] = *(const short8*)(SB + c * 128 + kb);
        bl[nt] = *(const short8*)(SB + 16384 + c * 128 + kb);
      }
      #pragma unroll
      for (int mt = 0; mt < 2; mt++)
        #pragma unroll
        for (int nt = 0; nt < 2; nt++) {
          f32x4 a0 = acc[mt][nt];
          a0 = __builtin_amdgcn_mfma_f32_16x16x32_bf16(ah[mt], bh[nt], a0, 0, 0, 0);
          a0 = __builtin_amdgcn_mfma_f32_16x16x32_bf16(al[mt], bh[nt], a0, 0, 0, 0);
          a0 = __builtin_amdgcn_mfma_f32_16x16x32_bf16(ah[mt], bl[nt], a0, 0, 0, 0);
          acc[mt][nt] = a0;
        }
    }
    #pragma unroll
    for (int mt = 0; mt < 2; mt++)
      #pragma unroll
      for (int nt = 0; nt < 2; nt++)
        #pragma unroll
        for (int r = 0; r < 4; r++) {
          int rloc = mt * 16 + (lane >> 4) * 4 + r;
          int col = wcol + nt * 16 + (lane & 15);
          stPutDual(sA, rloc, col, acc[mt][nt][r]);
        }
  }
  __syncthreads();
  // phase2: Mm strip = sA*Z
  {
    f32x4 acc[2][2] = {};
    #pragma unroll
    for (int ks = 0; ks < 4; ks++) {
      int kb = ks * 32 + (lane >> 4) * 8;
      short8 ah[2], al[2], bh[2], bl[2];
      #pragma unroll
      for (int mt = 0; mt < 2; mt++) {
        int rloc = mt * 16 + (lane & 15);
        ah[mt] = st8(sA, rloc, kb);
        al[mt] = st8(sA + 4096, rloc, kb);
      }
      #pragma unroll
      for (int nt = 0; nt < 2; nt++) {
        int c = wcol + nt * 16 + (lane & 15);
        bh[nt] = *(const short8*)(Z + c * 128 + kb);
        bl[nt] = *(const short8*)(Z + 16384 + c * 128 + kb);
      }
      #pragma unroll
      for (int mt = 0; mt < 2; mt++)
        #pragma unroll
        for (int nt = 0; nt < 2; nt++) {
          f32x4 a0 = acc[mt][nt];
          a0 = __builtin_amdgcn_mfma_f32_16x16x32_bf16(ah[mt], bh[nt], a0, 0, 0, 0);
          a0 = __builtin_amdgcn_mfma_f32_16x16x32_bf16(al[mt], bh[nt], a0, 0, 0, 0);
          a0 = __builtin_amdgcn_mfma_f32_16x16x32_bf16(ah[mt], bl[nt], a0, 0, 0, 0);
          acc[mt][nt] = a0;
        }
    }
    #pragma unroll
    for (int mt = 0; mt < 2; mt++)
      #pragma unroll
      for (int nt = 0; nt < 2; nt++)
        #pragma unroll
        for (int r = 0; r < 4; r++) {
          int rloc = mt * 16 + (lane >> 4) * 4 + r;
          int col = wcol + nt * 16 + (lane & 15);
          storeDual(Mm, (brow + rloc) * 128 + col, acc[mt][nt][r]);
        }
  }
}

// ---------------- K7: C2 strip (+tr M^4 partial) ----------------
__global__ __launch_bounds__(256) void k_c2(float* __restrict__ ws) {
  __shared__ float red[4];
  float* scal = ws + fSCAL;
  const unsigned short* Mm = MS(ws, sMm);
  int tid = threadIdx.x, b = blockIdx.x;
  int w = tid >> 6, lane = tid & 63;
  float tsum = mm_core(Mm, Mm, MS(ws, sC2), nullptr, 1.0f, 0.0f, 0.0f, b * 32, nullptr, 1.0f);
  #pragma unroll
  for (int off = 32; off > 0; off >>= 1) tsum += __shfl_down(tsum, off);
  if (lane == 0) red[w] = tsum;
  __syncthreads();
  if (tid == 0) scal[68 + b] = red[0] + red[1] + red[2] + red[3];
}

// interval from tr M^4 = ||C2||_F^2 (rigorous: lambda_max <= (tr M^4)^{1/4})
__device__ inline void interval_cs(const float* scal, float* c0o, float* iho) {
  float trM4 = scal[68] + scal[69] + scal[70] + scal[71];
  float Lam = 1.03f * sqrtf(sqrtf(fmaxf(trM4, 1e-37f)));
  float lo = -0.02f * Lam, hi = Lam;
  *c0o = 0.5f * (hi + lo);
  *iho = 1.0f / (0.5f * (hi - lo));
}

// ---------------- K8: XH, T2 elementwise ----------------
__global__ __launch_bounds__(256) void k_xh_t2(float* __restrict__ ws) {
  __shared__ float cs[2];
  float* scal = ws + fSCAL;
  if (threadIdx.x == 0) {
    float c0, ih;
    interval_cs(scal, &c0, &ih);
    cs[0] = c0; cs[1] = ih;
  }
  __syncthreads();
  float c0 = cs[0], ih = cs[1];
  float a2 = 2.0f * ih * ih, b2 = -4.0f * c0 * ih * ih, g2 = 2.0f * c0 * c0 * ih * ih - 1.0f;
  const unsigned short* Mm = MS(ws, sMm);
  const unsigned short* C2 = MS(ws, sC2);
  unsigned short* XH = MS(ws, sXH);
  unsigned short* T2 = MS(ws, sT2);
  int gid = blockIdx.x * 256 + threadIdx.x;
  #pragma unroll
  for (int t = 0; t < 4; t++) {
    int idx = gid * 4 + t;
    int row = idx >> 7, col = idx & 127;
    float m = valU(Mm, idx), c2v = valU(C2, idx);
    float dg = (row == col) ? 1.0f : 0.0f;
    storeDual(XH, idx, ih * m - ih * c0 * dg);
    storeDual(T2, idx, a2 * c2v + b2 * m + g2 * dg);
  }
}

// ---------------- K9: T3 = 2 XH T2 - XH (blk 0-3) | T4 = 2 T2^2 - I (blk 4-7) ----------------
__global__ __launch_bounds__(256) void k_t34(float* __restrict__ ws) {
  const unsigned short* XH = MS(ws, sXH);
  const unsigned short* T2 = MS(ws, sT2);
  if (blockIdx.x < 4) {
    mm_core(XH, T2, MS(ws, sT3), XH, 2.0f, -1.0f, 0.0f, blockIdx.x * 32, nullptr, 1.0f);
  } else {
    mm_core(T2, T2, MS(ws, sT4), nullptr, 2.0f, 0.0f, -1.0f, (blockIdx.x - 4) * 32, nullptr, 1.0f);
  }
}

// ---------------- K10: blk 0-3: T5 = 2 T3 T2 - XH; blk 4-19: G0..G4 ----------------
__global__ __launch_bounds__(256) void k_t5g(float* __restrict__ ws) {
  __shared__ float cs[8];
  __shared__ float sat[25];
  __shared__ float sc[25];
  float* scal = ws + fSCAL;
  int tid = threadIdx.x;
  if (blockIdx.x < 4) {
    mm_core(MS(ws, sT3), MS(ws, sT2), MS(ws, sT5), MS(ws, sXH),
            2.0f, -1.0f, 0.0f, blockIdx.x * 32, nullptr, 1.0f);
    return;
  }
  if (tid == 0) {
    float c0, ih;
    interval_cs(scal, &c0, &ih);
    float inv_s = scal[1];
    float t0 = (1.0f / 63.0f) / inv_s;
    float x0 = fminf(fmaxf((t0 - c0) * ih, -1.0f), 1.0f);
    cs[0] = acosf(x0); cs[1] = x0;
    cs[2] = 0.984375f * inv_s / ih;
  }
  __syncthreads();
  if (tid <= 24) {
    float th = cs[0], x0 = cs[1], SCc = cs[2];
    const float PI = 3.14159265358979f;
    float v;
    if (tid == 0) v = 0.5f * SCc * (2.0f / PI) * (sinf(th) - x0 * th);
    else if (tid == 1) v = SCc * (2.0f / PI) * (0.5f * th + 0.25f * sinf(2.0f * th) - x0 * sinf(th));
    else {
      float fj = (float)tid;
      v = SCc * (2.0f / PI) *
          (0.5f * (sinf((fj + 1.0f) * th) / (fj + 1.0f) + sinf((fj - 1.0f) * th) / (fj - 1.0f))
           - x0 * sinf(fj * th) / fj);
    }
    sat[tid] = v;
    sc[tid] = 0.f;
  }
  __syncthreads();
  if (tid == 0) {
    for (int j = 24; j >= 5; --j) {
      int k = j / 5, r = j - 5 * k;
      float aj = sat[j];
      if (r == 0) sc[k * 5] += aj;
      else { sc[k * 5 + r] += 2.0f * aj; sat[5 * k - r] -= aj; }
    }
    for (int r = 0; r < 5; r++) sc[r] += sat[r];
  }
  __syncthreads();
  const unsigned short* XH = MS(ws, sXH);
  const unsigned short* T2 = MS(ws, sT2);
  const unsigned short* T3 = MS(ws, sT3);
  const unsigned short* T4 = MS(ws, sT4);
  int bg = blockIdx.x - 4;
  int base = bg * 1024 + tid * 4;
  #pragma unroll
  for (int t = 0; t < 4; t++) {
    int idx = base + t;
    int row = idx >> 7, col = idx & 127;
    float dg = (row == col) ? 1.0f : 0.0f;
    float x1 = valU(XH, idx), x2 = valU(T2, idx), x3 = valU(T3, idx), x4 = valU(T4, idx);
    #pragma unroll
    for (int k = 0; k < 5; k++) {
      float g = sc[k * 5 + 0] * dg + sc[k * 5 + 1] * x1 + sc[k * 5 + 2] * x2 +
                sc[k * 5 + 3] * x3 + sc[k * 5 + 4] * x4;
      storeDual(MS(ws, sG0 + k), idx, g);
    }
  }
}

// ---------------- K11: strips T10 -> T15 -> T20 (T20 = 2 T15 T5 - T10) ----------------
__global__ __launch_bounds__(256) void k_thi(float* __restrict__ ws) {
  __shared__ unsigned short sA[8192]; // T10 strip
  __shared__ unsigned short sB[8192]; // T15 strip
  const unsigned short* T5 = MS(ws, sT5);
  unsigned short* T10 = MS(ws, sT10);
  unsigned short* T15 = MS(ws, sT15);
  unsigned short* T20 = MS(ws, sT20);
  int tid = threadIdx.x, b = blockIdx.x;
  int w = tid >> 6, lane = tid & 63;
  int brow = b * 32, wcol = w * 32;
  // phase1: T10 strip = 2*T5[rows]*T5 - I
  {
    f32x4 acc[2][2] = {};
    #pragma unroll
    for (int ks = 0; ks < 4; ks++) {
      int kb = ks * 32 + (lane >> 4) * 8;
      short8 ah[2], al[2], bh[2], bl[2];
      #pragma unroll
      for (int mt = 0; mt < 2; mt++) {
        int r = brow + mt * 16 + (lane & 15);
        ah[mt] = *(const short8*)(T5 + r * 128 + kb);
        al[mt] = *(const short8*)(T5 + 16384 + r * 128 + kb);
      }
      #pragma unroll
      for (int nt = 0; nt < 2; nt++) {
        int c = wcol + nt * 16 + (lane & 15);
        bh[nt] = *(const short8*)(T5 + c * 128 + kb);
        bl[nt] = *(const short8*)(T5 + 16384 + c * 128 + kb);
      }
      #pragma unroll
      for (int mt = 0; mt < 2; mt++)
        #pragma unroll
        for (int nt = 0; nt < 2; nt++) {
          f32x4 a0 = acc[mt][nt];
          a0 = __builtin_amdgcn_mfma_f32_16x16x32_bf16(ah[mt], bh[nt], a0, 0, 0, 0);
          a0 = __builtin_amdgcn_mfma_f32_16x16x32_bf16(al[mt], bh[nt], a0, 0, 0, 0);
          a0 = __builtin_amdgcn_mfma_f32_16x16x32_bf16(ah[mt], bl[nt], a0, 0, 0, 0);
          acc[mt][nt] = a0;
        }
    }
    #pragma unroll
    for (int mt = 0; mt < 2; mt++)
      #pragma unroll
      for (int nt = 0; nt < 2; nt++)
        #pragma unroll
        for (int r = 0; r < 4; r++) {
          int rloc = mt * 16 + (lane >> 4) * 4 + r;
          int col = wcol + nt * 16 + (lane & 15);
          int row = brow + rloc;
          float g = 2.0f * acc[mt][nt][r] - ((row == col) ? 1.0f : 0.0f);
          stPutDual(sA, rloc, col, g);
          storeDual(T10, row * 128 + col, g);
        }
  }
  __syncthreads();
  // phase2: T15 strip = 2*sA*T5 - T5[rows]
  {
    f32x4 acc[2][2] = {};
    #pragma unroll
    for (int ks = 0; ks < 4; ks++) {
      int kb = ks * 32 + (lane >> 4) * 8;
      short8 ah[2], al[2], bh[2], bl[2];
      #pragma unroll
      for (int mt = 0; mt < 2; mt++) {
        int rloc = mt * 16 + (lane & 15);
        ah[mt] = st8(sA, rloc, kb);
        al[mt] = st8(sA + 4096, rloc, kb);
      }
      #pragma unroll
      for (int nt = 0; nt < 2; nt++) {
        int c = wcol + nt * 16 + (lane & 15);
        bh[nt] = *(const short8*)(T5 + c * 128 + kb);
        bl[nt] = *(const short8*)(T5 + 16384 + c * 128 + kb);
      }
      #pragma unroll
      for (int mt = 0; mt < 2; mt++)
        #pragma unroll
        for (int nt = 0; nt < 2; nt++) {
          f32x4 a0 = acc[mt][nt];
          a0 = __builtin_amdgcn_mfma_f32_16x16x32_bf16(ah[mt], bh[nt], a0, 0, 0, 0);
          a0 = __builtin_amdgcn_mfma_f32_16x16x32_bf16(al[mt], bh[nt], a0, 0, 0, 0);
          a0 = __builtin_amdgcn_mfma_f32_16x16x32_bf16(ah[mt], bl[nt], a0, 0, 0, 0);
          acc[mt][nt] = a0;
        }
    }
    #pragma unroll
    for (int mt = 0; mt < 2; mt++)
      #pragma unroll
      for (int nt = 0; nt < 2; nt++)
        #pragma unroll
        for (int r = 0; r < 4; r++) {
          int rloc = mt * 16 + (lane >> 4) * 4 + r;
          int col = wcol + nt * 16 + (lane & 15);
          int idx = (brow + rloc) * 128 + col;
          float g = 2.0f * acc[mt][nt][r] - valU(T5, idx);
          stPutDual(sB, rloc, col, g);
          storeDual(T15, idx, g);
        }
  }
  __syncthreads();
  // phase3: T20 strip = 2*sB*T5 - sA(T10)
  {
    f32x4 acc[2][2] = {};
    #pragma unroll
    for (int ks = 0; ks < 4; ks++) {
      int kb = ks * 32 + (lane >> 4) * 8;
      short8 ah[2], al[2], bh[2], bl[2];
      #pragma unroll
      for (int mt = 0; mt < 2; mt++) {
        int rloc = mt * 16 + (lane & 15);
        ah[mt] = st8(sB, rloc, kb);
        al[mt] = st8(sB + 4096, rloc, kb);
      }
      #pragma unroll
      for (int nt = 0; nt < 2; nt++) {
        int c = wcol + nt * 16 + (lane & 15);
        bh[nt] = *(const short8*)(T5 + c * 128 + kb);
        bl[nt] = *(const short8*)(T5 + 16384 + c * 128 + kb);
      }
      #pragma unroll
      for (int mt = 0; mt < 2; mt++)
        #pragma unroll
        for (int nt = 0; nt < 2; nt++) {
          f32x4 a0 = acc[mt][nt];
          a0 = __builtin_amdgcn_mfma_f32_16x16x32_bf16(ah[mt], bh[nt], a0, 0, 0, 0);
          a0 = __builtin_amdgcn_mfma_f32_16x16x32_bf16(al[mt], bh[nt], a0, 0, 0, 0);
          a0 = __builtin_amdgcn_mfma_f32_16x16x32_bf16(ah[mt], bl[nt], a0, 0, 0, 0);
          acc[mt][nt] = a0;
        }
    }
    #pragma unroll
    for (int mt = 0; mt < 2; mt++)
      #pragma unroll
      for (int nt = 0; nt < 2; nt++)
        #pragma unroll
        for (int r = 0; r < 4; r++) {
          int rloc = mt * 16 + (lane >> 4) * 4 + r;
          int col = wcol + nt * 16 + (lane & 15);
          float g = 2.0f * acc[mt][nt][r] - stValU(sA, rloc, col);
          storeDual(T20, (brow + rloc) * 128 + col, g);
        }
  }
}

// ---------------- K12: F = G0 + T5 G1 + T10 G2 + T15 G3 + T20 G4 (+trF2) ----------------
__global__ __launch_bounds__(256) void k_bigF(float* __restrict__ ws) {
  __shared__ float red[4];
  float* scal = ws + fSCAL;
  const unsigned short* As[4] = { MS(ws, sT5), MS(ws, sT10), MS(ws, sT15), MS(ws, sT20) };
  const unsigned short* Bs[4] = { MS(ws, sG0 + 1), MS(ws, sG0 + 2), MS(ws, sG0 + 3), MS(ws, sG0 + 4) };
  const unsigned short* G0 = MS(ws, sG0);
  unsigned short* Fm = MS(ws, sF);
  int tid = threadIdx.x, b = blockIdx.x;
  int w = tid >> 6, lane = tid & 63;
  int brow = b * 32, wcol = w * 32;
  f32x4 acc[2][2] = {};
  for (int p = 0; p < 4; p++) {
    const unsigned short* A = As[p];
    const unsigned short* B = Bs[p];
    #pragma unroll
    for (int ks = 0; ks < 4; ks++) {
      int kb = ks * 32 + (lane >> 4) * 8;
      short8 ah[2], al[2], bh[2], bl[2];
      #pragma unroll
      for (int mt = 0; mt < 2; mt++) {
        int r = brow + mt * 16 + (lane & 15);
        ah[mt] = *(const short8*)(A + r * 128 + kb);
        al[mt] = *(const short8*)(A + 16384 + r * 128 + kb);
      }
      #pragma unroll
      for (int nt = 0; nt < 2; nt++) {
        int c = wcol + nt * 16 + (lane & 15);
        bh[nt] = *(const short8*)(B + c * 128 + kb);
        bl[nt] = *(const short8*)(B + 16384 + c * 128 + kb);
      }
      #pragma unroll
      for (int mt = 0; mt < 2; mt++)
        #pragma unroll
        for (int nt = 0; nt < 2; nt++) {
          f32x4 a0 = acc[mt][nt];
          a0 = __builtin_amdgcn_mfma_f32_16x16x32_bf16(ah[mt], bh[nt], a0, 0, 0, 0);
          a0 = __builtin_amdgcn_mfma_f32_16x16x32_bf16(al[mt], bh[nt], a0, 0, 0, 0);
          a0 = __builtin_amdgcn_mfma_f32_16x16x32_bf16(ah[mt], bl[nt], a0, 0, 0, 0);
          acc[mt][nt] = a0;
        }
    }
  }
  float tsum = 0.f;
  #pragma unroll
  for (int mt = 0; mt < 2; mt++)
    #pragma unroll
    for (int nt = 0; nt < 2; nt++)
      #pragma unroll
      for (int r = 0; r < 4; r++) {
        int row = brow + mt * 16 + (lane >> 4) * 4 + r;
        int col = wcol + nt * 16 + (lane & 15);
        int idx = row * 128 + col;
        float g = acc[mt][nt][r] + valU(G0, idx);
        storeDual(Fm, idx, g);
        tsum += g * g;
      }
  #pragma unroll
  for (int off = 32; off > 0; off >>= 1) tsum += __shfl_down(tsum, off);
  if (lane == 0) red[w] = tsum;
  __syncthreads();
  if (tid == 0) scal[72 + b] = red[0] + red[1] + red[2] + red[3];
}

// ---------------- K13: A1 strip (LDS) -> Bq strip -> Bbf ----------------
__global__ __launch_bounds__(256) void k_b(float* __restrict__ ws) {
  __shared__ unsigned short sA[8192];
  const unsigned short* Z = MS(ws, sZ);
  const unsigned short* Fm = MS(ws, sF);
  unsigned short* Bbf = (unsigned short*)(ws + fBBF);
  float aeff = ws[fSCAL + 7];
  int tid = threadIdx.x, b = blockIdx.x;
  int w = tid >> 6, lane = tid & 63;
  int brow = b * 32, wcol = w * 32;
  // phase1: A1 strip = Z[rows]*F
  {
    f32x4 acc[2][2] = {};
    #pragma unroll
    for (int ks = 0; ks < 4; ks++) {
      int kb = ks * 32 + (lane >> 4) * 8;
      short8 ah[2], al[2], bh[2], bl[2];
      #pragma unroll
      for (int mt = 0; mt < 2; mt++) {
        int r = brow + mt * 16 + (lane & 15);
        ah[mt] = *(const short8*)(Z + r * 128 + kb);
        al[mt] = *(const short8*)(Z + 16384 + r * 128 + kb);
      }
      #pragma unroll
      for (int nt = 0; nt < 2; nt++) {
        int c = wcol + nt * 16 + (lane & 15);
        bh[nt] = *(const short8*)(Fm + c * 128 + kb);
        bl[nt] = *(const short8*)(Fm + 16384 + c * 128 + kb);
      }
      #pragma unroll
      for (int mt = 0; mt < 2; mt++)
        #pragma unroll
        for (int nt = 0; nt < 2; nt++) {
          f32x4 a0 = acc[mt][nt];
          a0 = __builtin_amdgcn_mfma_f32_16x16x32_bf16(ah[mt], bh[nt], a0, 0, 0, 0);
          a0 = __builtin_amdgcn_mfma_f32_16x16x32_bf16(al[mt], bh[nt], a0, 0, 0, 0);
          a0 = __builtin_amdgcn_mfma_f32_16x16x32_bf16(ah[mt], bl[nt], a0, 0, 0, 0);
          acc[mt][nt] = a0;
        }
    }
    #pragma unroll
    for (int mt = 0; mt < 2; mt++)
      #pragma unroll
      for (int nt = 0; nt < 2; nt++)
        #pragma unroll
        for (int r = 0; r < 4; r++) {
          int rloc = mt * 16 + (lane >> 4) * 4 + r;
          int col = wcol + nt * 16 + (lane & 15);
          stPutDual(sA, rloc, col, acc[mt][nt][r]);
        }
  }
  __syncthreads();
  // phase2: Bbf strip = (sA*Z)*aeff (single-plane bf16)
  {
    f32x4 acc[2][2] = {};
    #pragma unroll
    for (int ks = 0; ks < 4; ks++) {
      int kb = ks * 32 + (lane >> 4) * 8;
      short8 ah[2], al[2], bh[2], bl[2];
      #pragma unroll
      for (int mt = 0; mt < 2; mt++) {
        int rloc = mt * 16 + (lane & 15);
        ah[mt] = st8(sA, rloc, kb);
        al[mt] = st8(sA + 4096, rloc, kb);
      }
      #pragma unroll
      for (int nt = 0; nt < 2; nt++) {
        int c = wcol + nt * 16 + (lane & 15);
        bh[nt] = *(const short8*)(Z + c * 128 + kb);
        bl[nt] = *(const short8*)(Z + 16384 + c * 128 + kb);
      }
      #pragma unroll
      for (int mt = 0; mt < 2; mt++)
        #pragma unroll
        for (int nt = 0; nt < 2; nt++) {
          f32x4 a0 = acc[mt][nt];
          a0 = __builtin_amdgcn_mfma_f32_16x16x32_bf16(ah[mt], bh[nt], a0, 0, 0, 0);
          a0 = __builtin_amdgcn_mfma_f32_16x16x32_bf16(al[mt], bh[nt], a0, 0, 0, 0);
          a0 = __builtin_amdgcn_mfma_f32_16x16x32_bf16(ah[mt], bl[nt], a0, 0, 0, 0);
          acc[mt][nt] = a0;
        }
    }
    #pragma unroll
    for (int mt = 0; mt < 2; mt++)
      #pragma unroll
      for (int nt = 0; nt < 2; nt++)
        #pragma unroll
        for (int r = 0; r < 4; r++) {
          int rloc = mt * 16 + (lane >> 4) * 4 + r;
          int col = wcol + nt * 16 + (lane & 15);
          Bbf[(brow + rloc) * 128 + col] = f2bf(acc[mt][nt][r] * aeff);
        }
  }
}

// ---------------- K14: V = test - mean; U = V*B; q; blk0: log_div ----------------
__global__ __launch_bounds__(256) void k_latent(const float* __restrict__ test, float* __restrict__ ws) {
  __shared__ unsigned short vh[16384];
  __shared__ float qs[128];
  int blk = blockIdx.x, tid = threadIdx.x;
  if (blk == 0 && tid == 0) {
    float* scal = ws + fSCAL;
    float trF2 = fmaxf(scal[72] + scal[73] + scal[74] + scal[75], 1e-30f);
    scal[0] = 0.5f * (128.0f * 1.8378770664093453f + 0.5f * logf(trF2));
  }
  const float* tb = test + blk * 128 * D;
  unsigned short* Vbf = (unsigned short*)(ws + fV);
  if (tid < 128) qs[tid] = 0.f;
  for (int idx = tid; idx < 16384; idx += 256) {
    int r = idx >> 7, c = idx & 127;
    float v = tb[idx] - ws[fMEAN + c];
    unsigned short h = f2bf(v);
    unsigned byte = ((unsigned)(r * 256 + c * 2)) ^ (((unsigned)(r & 7)) << 4);
    *(unsigned short*)((char*)vh + byte) = h;
    Vbf[blk * 16384 + idx] = h;
  }
  __syncthreads();
  int w = tid >> 6, lane = tid & 63;
  int wr = (w >> 1) * 64, wc = (w & 1) * 64;
  const unsigned short* Bbf = (const unsigned short*)(ws + fBBF);
  f32x4 acc[4][4] = {};
  for (int ks = 0; ks < 4; ks++) {
    int kb = ks * 32 + (lane >> 4) * 8;
    short8 af[4], bfv[4];
    #pragma unroll
    for (int mt = 0; mt < 4; mt++) {
      int r = wr + mt * 16 + (lane & 15);
      unsigned byte = ((unsigned)(r * 256 + kb * 2)) ^ (((unsigned)(r & 7)) << 4);
      af[mt] = *(short8*)((char*)vh + byte);
    }
    #pragma unroll
    for (int nt = 0; nt < 4; nt++) {
      int c = wc + nt * 16 + (lane & 15);
      bfv[nt] = *(const short8*)(Bbf + c * 128 + kb);
    }
    #pragma unroll
    for (int mt = 0; mt < 4; mt++)
      #pragma unroll
      for (int nt = 0; nt < 4; nt++)
        acc[mt][nt] = __builtin_amdgcn_mfma_f32_16x16x32_bf16(af[mt], bfv[nt], acc[mt][nt], 0, 0, 0);
  }
  unsigned short* Ubf = (unsigned short*)(ws + fU);
  #pragma unroll
  for (int mt = 0; mt < 4; mt++)
    #pragma unroll
    for (int nt = 0; nt < 4; nt++)
      #pragma unroll
      for (int r = 0; r < 4; r++) {
        int row = wr + mt * 16 + (lane >> 4) * 4 + r;
        int col = wc + nt * 16 + (lane & 15);
        Ubf[(blk * 128 + row) * 128 + col] = f2bf(acc[mt][nt][r]);
      }
  #pragma unroll
  for (int mt = 0; mt < 4; mt++)
    #pragma unroll
    for (int r = 0; r < 4; r++) {
      int row = wr + mt * 16 + (lane >> 4) * 4 + r;
      float p = 0.f;
      #pragma unroll
      for (int nt = 0; nt < 4; nt++) {
        int col = wc + nt * 16 + (lane & 15);
        unsigned byte = ((unsigned)(row * 256 + col * 2)) ^ (((unsigned)(row & 7)) << 4);
        p += bf2f(f2bf(acc[mt][nt][r])) * bf2f(*(unsigned short*)((char*)vh + byte));
      }
      p += __shfl_xor(p, 1, 16);
      p += __shfl_xor(p, 2, 16);
      p += __shfl_xor(p, 4, 16);
      p += __shfl_xor(p, 8, 16);
      if ((lane & 15) == 0) atomicAdd(&qs[row], p);  // exactly 2 adds/row
    }
  __syncthreads();
  if (tid < 128) ws[fQ + blk * 128 + tid] = qs[tid];
}

// ---------------- K15: out = 2 U V^T - q_i - q_j - log_div ----------------
__global__ __launch_bounds__(256) void k_pair(const float* __restrict__ ws, float* __restrict__ out) {
  __shared__ float qi[128];
  __shared__ float qj[128];
  __shared__ float sld;
  int bi = blockIdx.x, bj = blockIdx.y, tid = threadIdx.x;
  if (tid < 128) qi[tid] = ws[fQ + bi * 128 + tid];
  else qj[tid - 128] = ws[fQ + bj * 128 + (tid - 128)];
  if (tid == 0) sld = ws[fSCAL + 0];
  __syncthreads();
  int w = tid >> 6, lane = tid & 63;
  int wr = (w >> 1) * 64, wc = (w & 1) * 64;
  const unsigned short* Ubf = (const unsigned short*)(ws + fU);
  const unsigned short* Vbf = (const unsigned short*)(ws + fV);
  f32x4 acc[4][4] = {};
  for (int ks = 0; ks < 4; ks++) {
    int kb = ks * 32 + (lane >> 4) * 8;
    short8 af[4], bfv[4];
    #pragma unroll
    for (int mt = 0; mt < 4; mt++) {
      int r = bi * 128 + wr + mt * 16 + (lane & 15);
      af[mt] = *(const short8*)(Ubf + r * 128 + kb);
    }
    #pragma unroll
    for (int nt = 0; nt < 4; nt++) {
      int c = bj * 128 + wc + nt * 16 + (lane & 15);
      bfv[nt] = *(const short8*)(Vbf + c * 128 + kb);
    }
    #pragma unroll
    for (int mt = 0; mt < 4; mt++)
      #pragma unroll
      for (int nt = 0; nt < 4; nt++)
        acc[mt][nt] = __builtin_amdgcn_mfma_f32_16x16x32_bf16(af[mt], bfv[nt], acc[mt][nt], 0, 0, 0);
  }
  float ld = sld;
  #pragma unroll
  for (int mt = 0; mt < 4; mt++)
    #pragma unroll
    for (int nt = 0; nt < 4; nt++)
      #pragma unroll
      for (int r = 0; r < 4; r++) {
        int row = wr + mt * 16 + (lane >> 4) * 4 + r;
        int col = wc + nt * 16 + (lane & 15);
        float g = acc[mt][nt][r];
        out[(size_t)(bi * 128 + row) * MTEST + (bj * 128 + col)] =
          2.0f * g - qi[row] - qj[col] - ld;
      }
}

extern "C" void kernel_launch(void* const* d_in, const int* in_sizes, int n_in,
                              void* d_out, int out_size, void* d_ws, size_t ws_size,
                              hipStream_t stream) {
  (void)in_sizes; (void)n_in; (void)out_size; (void)ws_size;
  const float* X = (const float*)d_in[0];
  const float* test = (const float*)d_in[1];
  float* out = (float*)d_out;
  float* ws = (float*)d_ws;

  k_gt_partial<<<64, 256, 0, stream>>>(X, ws);
  k_reduce<<<64, 256, 0, stream>>>(ws);
  k_sbp<<<4, 256, 0, stream>>>(ws);        // SB + P
  k_pows<<<4, 256, 0, stream>>>(ws);       // P2->P3->P4 strips (+trP8)
  k_z<<<4, 256, 0, stream>>>(ws);          // Z
  k_m<<<4, 256, 0, stream>>>(ws);          // M1 strip -> Mm
  k_c2<<<4, 256, 0, stream>>>(ws);         // C2 (+trM4)
  k_xh_t2<<<16, 256, 0, stream>>>(ws);     // XH, T2
  k_t34<<<8, 256, 0, stream>>>(ws);        // T3 | T4
  k_t5g<<<20, 256, 0, stream>>>(ws);       // T5 | G0..G4
  k_thi<<<4, 256, 0, stream>>>(ws);        // T10->T15->T20 strips
  k_bigF<<<4, 256, 0, stream>>>(ws);       // F (+trF2)
  k_b<<<4, 256, 0, stream>>>(ws);          // A1 strip -> Bbf
  k_latent<<<64, 256, 0, stream>>>(test, ws);
  k_pair<<<dim3(64, 64), 256, 0, stream>>>(ws, out);
}